// Round 4
// baseline (2052.433 us; speedup 1.0000x reference)
//
#include <hip/hip_runtime.h>
#include <math.h>

#define NN 65536
#define EE 1048576
#define GG 512
#define D  128

// ---------------------------------------------------------------- GEMM, f64 accumulate
// C[M,N] = act(A @ B + bias); A: [M,K] (AT), B: [K,N] f32, C: [M,N] (OT)
// BM=BN=64, BK=16, 256 threads, 4x4 micro-tile, f64 FMA (exact vs np f64 ref)
template<typename AT, typename OT>
__global__ __launch_bounds__(256) void k_genc(const AT* __restrict__ A,
    const float* __restrict__ B, const float* __restrict__ bias,
    OT* __restrict__ C, int M, int N, int K, int relu)
{
    __shared__ double As[16][65];
    __shared__ double Bs[16][68];
    int tid = threadIdx.x;
    int tx = tid & 15, ty = tid >> 4;
    int row0 = blockIdx.y * 64, col0 = blockIdx.x * 64;
    double acc[4][4];
#pragma unroll
    for (int i = 0; i < 4; ++i)
#pragma unroll
        for (int j = 0; j < 4; ++j) acc[i][j] = 0.0;
    int ar = tid >> 2, ac = (tid & 3) * 4;   // A: 64 rows x 16 k
    int br = tid >> 4, bc = (tid & 15) * 4;  // B: 16 k x 64 cols
    for (int k0 = 0; k0 < K; k0 += 16) {
        const AT* ap = A + (size_t)(row0 + ar) * K + k0 + ac;
        As[ac + 0][ar] = (double)ap[0];
        As[ac + 1][ar] = (double)ap[1];
        As[ac + 2][ar] = (double)ap[2];
        As[ac + 3][ar] = (double)ap[3];
        const float* bp = B + (size_t)(k0 + br) * N + col0 + bc;
        Bs[br][bc + 0] = (double)bp[0];
        Bs[br][bc + 1] = (double)bp[1];
        Bs[br][bc + 2] = (double)bp[2];
        Bs[br][bc + 3] = (double)bp[3];
        __syncthreads();
#pragma unroll
        for (int kk = 0; kk < 16; ++kk) {
            double a[4], b[4];
#pragma unroll
            for (int i = 0; i < 4; ++i) a[i] = As[kk][ty * 4 + i];
#pragma unroll
            for (int j = 0; j < 4; ++j) b[j] = Bs[kk][tx * 4 + j];
#pragma unroll
            for (int i = 0; i < 4; ++i)
#pragma unroll
                for (int j = 0; j < 4; ++j) acc[i][j] = fma(a[i], b[j], acc[i][j]);
        }
        __syncthreads();
    }
#pragma unroll
    for (int i = 0; i < 4; ++i) {
#pragma unroll
        for (int j = 0; j < 4; ++j) {
            double v = acc[i][j] + (double)bias[col0 + tx * 4 + j];
            if (relu) v = fmax(v, 0.0);
            C[(size_t)(row0 + ty * 4 + i) * N + col0 + tx * 4 + j] = (OT)v;
        }
    }
}

// ---------------------------------------------------------------- CSR build
__global__ __launch_bounds__(256) void k_hist(const int* __restrict__ Wr, int* __restrict__ cnt)
{
    int e = blockIdx.x * 256 + threadIdx.x;
    if (e < EE) atomicAdd(&cnt[Wr[e]], 1);
}

__global__ __launch_bounds__(256) void k_scan1(const int* __restrict__ cnt,
    int* __restrict__ excl, int* __restrict__ bsum)
{
    __shared__ int s[256];
    int b = blockIdx.x, t = threadIdx.x;
    int v = cnt[b * 256 + t];
    s[t] = v; __syncthreads();
    for (int o = 1; o < 256; o <<= 1) {
        int x = (t >= o) ? s[t - o] : 0;
        __syncthreads();
        s[t] += x;
        __syncthreads();
    }
    excl[b * 256 + t] = s[t] - v;
    if (t == 255) bsum[b] = s[255];
}

__global__ void k_scan2(const int* __restrict__ bsum, int* __restrict__ boff)
{
    __shared__ int s[256];
    int t = threadIdx.x;
    int v = bsum[t]; s[t] = v; __syncthreads();
    for (int o = 1; o < 256; o <<= 1) {
        int x = (t >= o) ? s[t - o] : 0;
        __syncthreads();
        s[t] += x;
        __syncthreads();
    }
    boff[t] = s[t] - v;
}

__global__ __launch_bounds__(256) void k_scan3(const int* __restrict__ excl, const int* __restrict__ boff,
    int* __restrict__ rowptr, int* __restrict__ cursor)
{
    int i = blockIdx.x * 256 + threadIdx.x;
    int v = excl[i] + boff[i >> 8];
    rowptr[i] = v; cursor[i] = v;
    if (i == 0) rowptr[NN] = EE;
}

__global__ __launch_bounds__(256) void k_scatter(const int* __restrict__ Wr, const int* __restrict__ Wc,
    const float* __restrict__ Wv, int* __restrict__ cursor, int* __restrict__ ecol, float* __restrict__ ev)
{
    int e = blockIdx.x * 256 + threadIdx.x;
    if (e >= EE) return;
    int r = Wr[e];
    int p = atomicAdd(&cursor[r], 1);
    ecol[p] = Wc[e]; ev[p] = Wv[e];
}

// ---------------------------------------------------------------- SpMM (CSR, one wave per row, f64 accum)
template<typename T>
__global__ __launch_bounds__(256) void k_spmm_csr(const int* __restrict__ rowptr,
    const int* __restrict__ ecol, const float* __restrict__ eval,
    const T* __restrict__ X, T* __restrict__ Y)
{
    int row = blockIdx.x * 4 + (threadIdx.x >> 6);
    int lane = threadIdx.x & 63;
    int s = rowptr[row], e = rowptr[row + 1];
    double a0 = 0.0, a1 = 0.0;
    for (int i = s; i < e; ++i) {
        int cc = ecol[i];
        double w = (double)eval[i];
        const T* xr = X + (size_t)cc * D + lane * 2;
        a0 = fma(w, (double)xr[0], a0);
        a1 = fma(w, (double)xr[1], a1);
    }
    T* yr = Y + (size_t)row * D + lane * 2;
    yr[0] = (T)a0; yr[1] = (T)a1;
}

// ---------------------------------------------------------------- BN stats (deterministic tree, f64)
template<typename T>
__global__ __launch_bounds__(128) void k_bnstats(const T* __restrict__ X,
    double* __restrict__ psum, double* __restrict__ pssq)
{
    int d = threadIdx.x;
    int r0 = blockIdx.x * 256;
    double s = 0.0, q = 0.0;
    for (int r = r0; r < r0 + 256; ++r) {
        double v = (double)X[(size_t)r * D + d];
        s += v; q = fma(v, v, q);
    }
    psum[blockIdx.x * 128 + d] = s;
    pssq[blockIdx.x * 128 + d] = q;
}

__global__ void k_bnfin(const double* __restrict__ psum, const double* __restrict__ pssq,
    const float* __restrict__ gamma, const float* __restrict__ beta,
    double* __restrict__ a, double* __restrict__ c, int nb, int layer)
{
    int t = threadIdx.x;
    if (t >= nb * 128) return;
    int blk = t >> 7, d = t & 127;
    const double* ps = psum + blk * 32768;
    const double* pq = pssq + blk * 32768;
    double s = 0.0, q = 0.0;
    for (int j = 0; j < 256; ++j) { s += ps[j * 128 + d]; q += pq[j * 128 + d]; }
    double m = s * (1.0 / 65536.0);
    double v = q * (1.0 / 65536.0) - m * m;
    double aa = (double)gamma[layer * 128 + d] / sqrt(v + 1e-5);
    a[t] = aa;
    c[t] = (double)beta[layer * 128 + d] - m * aa;
}

// ---------------------------------------------------------------- elementwise (f64 math)
template<typename T>
__global__ __launch_bounds__(256) void k_mean2(const T* __restrict__ x0, const T* __restrict__ x1,
                                               T* __restrict__ o)
{
    int i = blockIdx.x * 256 + threadIdx.x;
    o[i] = (T)(0.5 * ((double)x0[i] + (double)x1[i]));
}

template<typename T>
__global__ __launch_bounds__(256) void k_hidden(const T* __restrict__ p0, const T* __restrict__ p1,
    const double* __restrict__ a, const double* __restrict__ c, T* __restrict__ o)
{
    int i = blockIdx.x * 256 + threadIdx.x;
    int d = i & 127;
    double x = (double)p0[i], y = (double)p1[i];
    double r = 0.5 * (fmax(fma(x, a[d], c[d]), 0.0) + fmax(fma(y, a[128 + d], c[128 + d]), 0.0));
    o[i] = (T)r;
}

// ---------------------------------------------------------------- concat MLP (f64)
template<typename T>
__global__ __launch_bounds__(256) void k_concat(const T* __restrict__ h0, const T* __restrict__ h1,
    const T* __restrict__ h2, const T* __restrict__ h3,
    const float* __restrict__ w1, const float* __restrict__ b1,
    const float* __restrict__ w2, const float* __restrict__ b2,
    double* __restrict__ Hpre)
{
    __shared__ double sw0[128], sw1_[128], sw2_[128], sw3[128], sv[128], sb[128];
    int t = threadIdx.x;
    if (t < 128) {
        sw0[t] = (double)w1[t];        sw1_[t] = (double)w1[128 + t];
        sw2_[t] = (double)w1[256 + t]; sw3[t]  = (double)w1[384 + t];
        sv[t]  = (double)w2[t];        sb[t]   = (double)b1[t];
    }
    __syncthreads();
    int i = blockIdx.x * 256 + t;
    double x0 = (double)h0[i], x1 = (double)h1[i], x2 = (double)h2[i], x3 = (double)h3[i];
    double acc = (double)b2[0];
#pragma unroll 8
    for (int h = 0; h < D; ++h) {
        double tt = fma(x3, sw3[h], fma(x2, sw2_[h], fma(x1, sw1_[h], fma(x0, sw0[h], sb[h]))));
        acc = fma(fmax(tt, 0.0), sv[h], acc);
    }
    Hpre[i] = acc;
}

// BN+relu on H (f64 in place) + f32 output copy
__global__ __launch_bounds__(256) void k_bnapplyH(double* __restrict__ Hp,
    const double* __restrict__ a, const double* __restrict__ c, float* __restrict__ oH)
{
    int i = blockIdx.x * 256 + threadIdx.x;
    int d = i & 127;
    double v = fmax(fma(Hp[i], a[d], c[d]), 0.0);
    Hp[i] = v;
    oH[i] = (float)v;
}

// ---------------------------------------------------------------- S = softmax(hid2 @ w2 + b2) (f64)
__global__ __launch_bounds__(256) void k_s(const double* __restrict__ hid,
    const float* __restrict__ w2, const float* __restrict__ b2,
    float* __restrict__ S, double* __restrict__ S64)
{
    int n = blockIdx.x * 256 + threadIdx.x;
    if (n >= NN) return;
    const double* hr = hid + (size_t)n * D;
    double s[10];
#pragma unroll
    for (int k = 0; k < 10; ++k) s[k] = (double)b2[k];
    for (int h = 0; h < D; ++h) {
        double hv = hr[h];
#pragma unroll
        for (int k = 0; k < 10; ++k) s[k] = fma(hv, (double)w2[h * 10 + k], s[k]);
    }
    double m = s[0];
#pragma unroll
    for (int k = 1; k < 10; ++k) m = fmax(m, s[k]);
    double e[10], sum = 0.0;
#pragma unroll
    for (int k = 0; k < 10; ++k) { e[k] = exp(s[k] - m); sum += e[k]; }
    double inv = 1.0 / sum;
#pragma unroll
    for (int k = 0; k < 10; ++k) {
        double v = e[k] * inv;
        S[(size_t)n * 10 + k] = (float)v;
        S64[(size_t)n * 10 + k] = v;
    }
}

// ---------------------------------------------------------------- E_all (f64)
__global__ __launch_bounds__(256) void k_eall(const double* __restrict__ S64, const double* __restrict__ H,
    const int* __restrict__ off, float* __restrict__ Eo, double* __restrict__ E64)
{
    int g = blockIdx.x;
    int d = threadIdx.x & 127;
    int half = threadIdx.x >> 7;
    double acc[5] = {0.0, 0.0, 0.0, 0.0, 0.0};
    int s0 = off[g], s1 = off[g + 1];
    for (int n = s0; n < s1; ++n) {
        double hv = H[(size_t)n * D + d];
#pragma unroll
        for (int j = 0; j < 5; ++j) acc[j] = fma(S64[(size_t)n * 10 + half * 5 + j], hv, acc[j]);
    }
#pragma unroll
    for (int j = 0; j < 5; ++j) {
        size_t o = (size_t)g * 1280 + (half * 5 + j) * D + d;
        Eo[o] = (float)acc[j];
        E64[o] = acc[j];
    }
}

// ---------------------------------------------------------------- graph offsets
__global__ void k_off(const int* __restrict__ gi, int* __restrict__ off)
{
    int g = blockIdx.x * 256 + threadIdx.x;
    if (g > GG) return;
    int lo = 0, hi = NN;
    while (lo < hi) { int mid = (lo + hi) >> 1; if (gi[mid] < g) lo = mid + 1; else hi = mid; }
    off[g] = lo;
}

// ---------------------------------------------------------------- corr
__global__ void k_corr(const float* __restrict__ ci, const float* __restrict__ ca, float* __restrict__ corr)
{
    int t = threadIdx.x;
    if (t >= 160) return;
    int r = t / 16, c = t % 16;
    double m = -1e300;
    for (int i = 0; i < 10; ++i) m = fmax(m, (double)ci[i * 16 + c]);
    double s = 0.0;
    for (int i = 0; i < 10; ++i) s += exp((double)ci[i * 16 + c] - m);
    double vi = exp((double)ci[r * 16 + c] - m) / s;
    double m2 = -1e300;
    for (int j = 0; j < 16; ++j) m2 = fmax(m2, (double)ca[r * 16 + j]);
    double s2 = 0.0;
    for (int j = 0; j < 16; ++j) s2 += exp((double)ca[r * 16 + j] - m2);
    double va = exp((double)ca[r * 16 + c] - m2) / s2;
    corr[t] = (float)(vi * va);
}

// ---------------------------------------------------------------- JAX threefry gumbel — PARTITIONABLE path
// (jax_threefry_partitionable=True, default since JAX 0.4.30)
// per element i: counter64 = i -> (x0,x1) = (hi32=0, lo32=i); bits = out0 ^ out1
__device__ __forceinline__ unsigned tf_rotl(unsigned x, unsigned n) { return (x << n) | (x >> (32u - n)); }

__global__ void k_gumbel(double* __restrict__ out)
{
    int i = blockIdx.x * 256 + threadIdx.x;
    if (i >= 5120) return;
    unsigned x0 = 0u;              // hi32 of 64-bit counter (size 5120 < 2^32)
    unsigned x1 = (unsigned)i;     // lo32
    const unsigned ks0 = 0u, ks1 = 42u;
    const unsigned ks2 = 0x1BD11BDAu ^ ks0 ^ ks1;
    x0 += ks0; x1 += ks1;
#define TF_ROUND(rr) { x0 += x1; x1 = tf_rotl(x1, rr); x1 ^= x0; }
    TF_ROUND(13) TF_ROUND(15) TF_ROUND(26) TF_ROUND(6)
    x0 += ks1; x1 += ks2 + 1u;
    TF_ROUND(17) TF_ROUND(29) TF_ROUND(16) TF_ROUND(24)
    x0 += ks2; x1 += ks0 + 2u;
    TF_ROUND(13) TF_ROUND(15) TF_ROUND(26) TF_ROUND(6)
    x0 += ks0; x1 += ks1 + 3u;
    TF_ROUND(17) TF_ROUND(29) TF_ROUND(16) TF_ROUND(24)
    x0 += ks1; x1 += ks2 + 4u;
    TF_ROUND(13) TF_ROUND(15) TF_ROUND(26) TF_ROUND(6)
    x0 += ks2; x1 += ks0 + 5u;
#undef TF_ROUND
    unsigned bits = x0 ^ x1;       // 32-bit output combine (partitionable path)
    unsigned fb = (bits >> 9) | 0x3f800000u;
    float f = __uint_as_float(fb) - 1.0f;  // exact float in [0,1)
    const float tinyf = 1.1754943508222875e-38f;
    float u32v = fmaxf(tinyf, f * (1.0f - tinyf) + tinyf);  // XLA f32 uniform, bit-exact
    out[i] = -log(-log((double)u32v));
}

// ---------------------------------------------------------------- pred1 + sampling (f64)
__global__ __launch_bounds__(64) void k_pred1(const double* __restrict__ E64, const float* __restrict__ fw,
    const float* __restrict__ fb, const double* __restrict__ gum, const int* __restrict__ tgt,
    const float* __restrict__ corr, float* __restrict__ pred1, float* __restrict__ ind,
    float* __restrict__ cmask)
{
    int g = blockIdx.x;
    int l = threadIdx.x;
    double acc[10];
#pragma unroll
    for (int c = 0; c < 10; ++c) acc[c] = 0.0;
    for (int i = l; i < 1280; i += 64) {
        double e = E64[(size_t)g * 1280 + i];
#pragma unroll
        for (int c = 0; c < 10; ++c) acc[c] = fma(e, (double)fw[i * 10 + c], acc[c]);
    }
#pragma unroll
    for (int c = 0; c < 10; ++c) {
        double v = acc[c];
        for (int o = 32; o > 0; o >>= 1) v += __shfl_down(v, o, 64);
        acc[c] = v;
    }
    if (l == 0) {
        double best = -1e300; int bi = 0;
        for (int c = 0; c < 10; ++c) {
            double p = acc[c] + (double)fb[c];
            pred1[g * 10 + c] = (float)p;
            double y = p + gum[g * 10 + c];
            if (y > best) { best = y; bi = c; }
        }
        ind[g] = (bi == tgt[g]) ? 1.f : 0.f;
        for (int f = 0; f < 16; ++f) cmask[g * 16 + f] = corr[bi * 16 + f];
    }
}

// ---------------------------------------------------------------- Q + feature_mask (f32)
__global__ __launch_bounds__(128) void k_q(const float* __restrict__ Eo, const float* __restrict__ w1,
    const float* __restrict__ b1, const float* __restrict__ w2, const float* __restrict__ b2,
    const float* __restrict__ cmask, float* __restrict__ Q, float* __restrict__ fm)
{
    int gk = blockIdx.x;
    int g = gk / 10;
    int h = threadIdx.x;
    __shared__ float e[128];
    __shared__ float hh[128];
    __shared__ float qv[16];
    __shared__ float pr[16];
    e[h] = Eo[(size_t)gk * D + h];
    __syncthreads();
    float acc = b1[h];
#pragma unroll 8
    for (int d = 0; d < D; ++d) acc = fmaf(e[d], w1[d * D + h], acc);
    hh[h] = fmaxf(acc, 0.f);
    __syncthreads();
    if (h < 16) {
        float s = b2[h];
        for (int d = 0; d < D; ++d) s = fmaf(hh[d], w2[d * 16 + h], s);
        qv[h] = s;
    }
    __syncthreads();
    if (h < 16) {
        float m = qv[0];
        for (int f = 1; f < 16; ++f) m = fmaxf(m, qv[f]);
        pr[h] = expf(qv[h] - m);
    }
    __syncthreads();
    if (h < 16) {
        float s = 0.f;
        for (int f = 0; f < 16; ++f) s += pr[f];
        float q = pr[h] / s;
        Q[(size_t)gk * 16 + h] = q;
        qv[h] = q * cmask[g * 16 + h];
    }
    __syncthreads();
    if (h == 0) {
        float s = 0.f;
        for (int f = 0; f < 16; ++f) s += qv[f];
        fm[gk] = s;
    }
}

// ---------------------------------------------------------------- pred2 (f64 accum)
__global__ __launch_bounds__(64) void k_pred2(const double* __restrict__ E64, const float* __restrict__ fw,
    const float* __restrict__ fb, const float* __restrict__ fm, float* __restrict__ pred2)
{
    int g = blockIdx.x;
    int l = threadIdx.x;
    double acc[10];
#pragma unroll
    for (int c = 0; c < 10; ++c) acc[c] = 0.0;
    for (int i = l; i < 1280; i += 64) {
        int k = i >> 7;
        double e = E64[(size_t)g * 1280 + i] * (double)fm[g * 10 + k];
#pragma unroll
        for (int c = 0; c < 10; ++c) acc[c] = fma(e, (double)fw[i * 10 + c], acc[c]);
    }
#pragma unroll
    for (int c = 0; c < 10; ++c) {
        double v = acc[c];
        for (int o = 32; o > 0; o >>= 1) v += __shfl_down(v, o, 64);
        acc[c] = v;
    }
    if (l == 0)
        for (int c = 0; c < 10; ++c) pred2[g * 10 + c] = (float)(acc[c] + (double)fb[c]);
}

// ================================================================ host
extern "C" void kernel_launch(void* const* d_in, const int* in_sizes, int n_in,
                              void* d_out, int out_size, void* d_ws, size_t ws_size,
                              hipStream_t stream)
{
    const float* features = (const float*)d_in[0];
    const int*   W_row    = (const int*)d_in[1];
    const int*   W_col    = (const int*)d_in[2];
    const float* W_vals   = (const float*)d_in[3];
    const int*   gi       = (const int*)d_in[4];
    const int*   targets  = (const int*)d_in[5];
    const float* enc_w1   = (const float*)d_in[6];
    const float* enc_b1   = (const float*)d_in[7];
    const float* enc_w2   = (const float*)d_in[8];
    const float* enc_b2   = (const float*)d_in[9];
    const float* bn_gamma = (const float*)d_in[10];
    const float* bn_beta  = (const float*)d_in[11];
    const float* concat_w1= (const float*)d_in[12];
    const float* concat_b1= (const float*)d_in[13];
    const float* concat_w2= (const float*)d_in[14];
    const float* concat_b2= (const float*)d_in[15];
    const float* smlp_w1  = (const float*)d_in[16];
    const float* smlp_b1  = (const float*)d_in[17];
    const float* smlp_w2  = (const float*)d_in[18];
    const float* smlp_b2  = (const float*)d_in[19];
    const float* proto_w1 = (const float*)d_in[20];
    const float* proto_b1 = (const float*)d_in[21];
    const float* proto_w2 = (const float*)d_in[22];
    const float* proto_b2 = (const float*)d_in[23];
    const float* final_w  = (const float*)d_in[24];
    const float* final_b  = (const float*)d_in[25];
    const float* corr_i   = (const float*)d_in[26];
    const float* corr_a   = (const float*)d_in[27];

    float* out = (float*)d_out;
    float* o_pred1 = out + 0;
    float* o_pred2 = out + 5120;
    float* o_S     = out + 10240;
    float* o_H     = out + 665600;
    float* o_ind   = out + 9054208;
    float* o_E     = out + 9054720;
    float* o_Q     = out + 9710080;

    // ---------------- workspace arena
    char* base = (char*)d_ws;
    size_t off = 0;
    auto alloc = [&](size_t n) -> char* {
        char* r = base + off;
        off = (off + n + 255) & ~(size_t)255;
        return r;
    };
    int*    d_off   = (int*)alloc(513 * 4);
    double* d_a     = (double*)alloc(256 * 8);
    double* d_c     = (double*)alloc(256 * 8);
    double* d_gum   = (double*)alloc(5120 * 8);
    float*  d_corr  = (float*)alloc(160 * 4);
    float*  d_cmask = (float*)alloc(512 * 16 * 4);
    float*  d_fm    = (float*)alloc(5120 * 4);
    double* psum    = (double*)alloc(2 * 256 * 128 * 8);
    double* pssq    = (double*)alloc(2 * 256 * 128 * 8);
    int*    cnt     = (int*)alloc((size_t)NN * 4);
    int*    excl    = (int*)alloc((size_t)NN * 4);
    int*    bsum    = (int*)alloc(256 * 4);
    int*    boff    = (int*)alloc(256 * 4);
    int*    rowptr  = (int*)alloc((size_t)(NN + 1) * 4);
    int*    cursor  = (int*)alloc((size_t)NN * 4);
    int*    ecol    = (int*)alloc((size_t)EE * 4);
    float*  evalv   = (float*)alloc((size_t)EE * 4);

    const size_t S4 = (size_t)NN * D * 4;   // 32 MiB
    const size_t S8 = S4 * 2;               // 64 MiB
    size_t remain = (ws_size > off) ? (ws_size - off) : 0;
    int big = remain >= 7 * S8;             // full-f64 storage if it fits
    size_t SZ = big ? S8 : S4;

    char* rot0 = base + off;
    char* rot1 = rot0 + SZ;
    char* rot2 = rot1 + SZ;
    char* h0 = rot2 + SZ;
    char* h1 = h0 + SZ;
    char* h2 = h1 + SZ;
    char* h3 = h2 + SZ;
    char* Tenc = h0;                         // N x 256 elems = 2*SZ (h0+h1), dead before h0 written
    double* H64  = (double*)rot0;            // 64 MiB (rot region dead after prop loop)
    double* S64  = (double*)h0;              // h region dead after concat
    double* E64  = (double*)(h0 + 8 * 1024 * 1024);
    double* hid2 = (double*)(h0 + 16 * 1024 * 1024);

    // ---------------- small precomputations
    k_off   <<<3, 256, 0, stream>>>(gi, d_off);
    k_corr  <<<1, 256, 0, stream>>>(corr_i, corr_a, d_corr);
    k_gumbel<<<20, 256, 0, stream>>>(d_gum);

    // ---------------- CSR build (per call; deterministic up to within-row order)
    hipMemsetAsync(cnt, 0, (size_t)NN * 4, stream);
    k_hist   <<<EE / 256, 256, 0, stream>>>(W_row, cnt);
    k_scan1  <<<256, 256, 0, stream>>>(cnt, excl, bsum);
    k_scan2  <<<1, 256, 0, stream>>>(bsum, boff);
    k_scan3  <<<256, 256, 0, stream>>>(excl, boff, rowptr, cursor);
    k_scatter<<<EE / 256, 256, 0, stream>>>(W_row, W_col, W_vals, cursor, ecol, evalv);

    // ---------------- encoder (f64 accumulation)
    if (big) {
        double* T = (double*)Tenc;
        k_genc<float,  double><<<dim3(4, 1024), 256, 0, stream>>>(features, enc_w1,             enc_b1,       T,              NN, 256, 128, 1);
        k_genc<double, double><<<dim3(2, 1024), 256, 0, stream>>>(T,        enc_w2,             enc_b2,       (double*)rot0,  NN, 128, 256, 0);
        k_genc<float,  double><<<dim3(4, 1024), 256, 0, stream>>>(features, enc_w1 + 128 * 256, enc_b1 + 256, T,              NN, 256, 128, 1);
        k_genc<double, double><<<dim3(2, 1024), 256, 0, stream>>>(T,        enc_w2 + 256 * 128, enc_b2 + 128, (double*)rot1,  NN, 128, 256, 0);
        k_mean2<double><<<32768, 256, 0, stream>>>((const double*)rot0, (const double*)rot1, (double*)h0);
    } else {
        float* T = (float*)Tenc;
        k_genc<float, float><<<dim3(4, 1024), 256, 0, stream>>>(features, enc_w1,             enc_b1,       T,             NN, 256, 128, 1);
        k_genc<float, float><<<dim3(2, 1024), 256, 0, stream>>>(T,        enc_w2,             enc_b2,       (float*)rot0,  NN, 128, 256, 0);
        k_genc<float, float><<<dim3(4, 1024), 256, 0, stream>>>(features, enc_w1 + 128 * 256, enc_b1 + 256, T,             NN, 256, 128, 1);
        k_genc<float, float><<<dim3(2, 1024), 256, 0, stream>>>(T,        enc_w2 + 256 * 128, enc_b2 + 128, (float*)rot1,  NN, 128, 256, 0);
        k_mean2<float><<<32768, 256, 0, stream>>>((const float*)rot0, (const float*)rot1, (float*)h0);
    }

    // ---------------- propagation loop
    char* cur0 = rot0;
    char* cur1 = rot1;
    char* fre  = rot2;
    char* hbuf[4] = { h0, h1, h2, h3 };
    for (int p = 0; p < 3; ++p) {
        if (big) {
            k_spmm_csr<double><<<NN / 4, 256, 0, stream>>>(rowptr, ecol, evalv, (const double*)cur0, (double*)fre);
            k_spmm_csr<double><<<NN / 4, 256, 0, stream>>>(rowptr, ecol, evalv, (const double*)cur1, (double*)cur0);
            k_bnstats<double><<<256, 128, 0, stream>>>((const double*)fre,  psum, pssq);
            k_bnstats<double><<<256, 128, 0, stream>>>((const double*)cur0, psum + 32768, pssq + 32768);
            k_bnfin<<<1, 256, 0, stream>>>(psum, pssq, bn_gamma, bn_beta, d_a, d_c, 2, p);
            k_hidden<double><<<32768, 256, 0, stream>>>((const double*)fre, (const double*)cur0, d_a, d_c, (double*)hbuf[1 + p]);
        } else {
            k_spmm_csr<float><<<NN / 4, 256, 0, stream>>>(rowptr, ecol, evalv, (const float*)cur0, (float*)fre);
            k_spmm_csr<float><<<NN / 4, 256, 0, stream>>>(rowptr, ecol, evalv, (const float*)cur1, (float*)cur0);
            k_bnstats<float><<<256, 128, 0, stream>>>((const float*)fre,  psum, pssq);
            k_bnstats<float><<<256, 128, 0, stream>>>((const float*)cur0, psum + 32768, pssq + 32768);
            k_bnfin<<<1, 256, 0, stream>>>(psum, pssq, bn_gamma, bn_beta, d_a, d_c, 2, p);
            k_hidden<float><<<32768, 256, 0, stream>>>((const float*)fre, (const float*)cur0, d_a, d_c, (float*)hbuf[1 + p]);
        }
        char* t0 = fre; char* t1 = cur0; char* t2 = cur1;
        cur0 = t0; cur1 = t1; fre = t2;
    }

    // ---------------- concat MLP -> H64 (rot region), BN, outputs
    if (big)
        k_concat<double><<<32768, 256, 0, stream>>>((const double*)h0, (const double*)h1, (const double*)h2, (const double*)h3,
                                                    concat_w1, concat_b1, concat_w2, concat_b2, H64);
    else
        k_concat<float><<<32768, 256, 0, stream>>>((const float*)h0, (const float*)h1, (const float*)h2, (const float*)h3,
                                                   concat_w1, concat_b1, concat_w2, concat_b2, H64);
    k_bnstats<double><<<256, 128, 0, stream>>>(H64, psum, pssq);
    k_bnfin<<<1, 256, 0, stream>>>(psum, pssq, bn_gamma, bn_beta, d_a, d_c, 1, 3);
    k_bnapplyH<<<32768, 256, 0, stream>>>(H64, d_a, d_c, o_H);

    // ---------------- S_all (f64)
    k_genc<double, double><<<dim3(2, 1024), 256, 0, stream>>>(H64, smlp_w1, smlp_b1, hid2, NN, 128, 128, 1);
    k_s<<<256, 256, 0, stream>>>(hid2, smlp_w2, smlp_b2, o_S, S64);

    // ---------------- E_all, heads
    k_eall <<<512, 256, 0, stream>>>(S64, H64, d_off, o_E, E64);
    k_pred1<<<512, 64, 0, stream>>>(E64, final_w, final_b, d_gum, targets, d_corr,
                                    o_pred1, o_ind, d_cmask);
    k_q    <<<5120, 128, 0, stream>>>(o_E, proto_w1, proto_b1, proto_w2, proto_b2,
                                      d_cmask, o_Q, d_fm);
    k_pred2<<<512, 64, 0, stream>>>(E64, final_w, final_b, d_fm, o_pred2);

    (void)in_sizes; (void)n_in; (void)out_size;
}

// Round 5
// 1591.053 us; speedup vs baseline: 1.2900x; 1.2900x over previous
//
#include <hip/hip_runtime.h>
#include <math.h>

#define NN 65536
#define EE 1048576
#define GG 512
#define D  128

typedef float4 f4;

// ---------------------------------------------------------------- GEMM (fp32, 128x128 tile, 8x8 micro)
// C[M,N] = act(A[M,K] @ B[K,N] + bias[N]); M%128==0, N%128==0, K%16==0
__global__ __launch_bounds__(256) void k_gemm(const float* __restrict__ A,
    const float* __restrict__ B, const float* __restrict__ bias,
    float* __restrict__ C, int M, int N, int K, int relu)
{
    __shared__ __align__(16) float As[16][132];
    __shared__ __align__(16) float Bs[16][132];
    int tid = threadIdx.x;
    int tx = tid & 15, ty = tid >> 4;
    int row0 = blockIdx.y * 128, col0 = blockIdx.x * 128;
    float acc[8][8];
#pragma unroll
    for (int i = 0; i < 8; ++i)
#pragma unroll
        for (int j = 0; j < 8; ++j) acc[i][j] = 0.f;
    int ar = tid >> 1, ac = (tid & 1) * 8;
    int br = tid >> 4, bc = (tid & 15) * 8;
    for (int k0 = 0; k0 < K; k0 += 16) {
        f4 a0 = *(const f4*)(A + (size_t)(row0 + ar) * K + k0 + ac);
        f4 a1 = *(const f4*)(A + (size_t)(row0 + ar) * K + k0 + ac + 4);
        As[ac + 0][ar] = a0.x; As[ac + 1][ar] = a0.y; As[ac + 2][ar] = a0.z; As[ac + 3][ar] = a0.w;
        As[ac + 4][ar] = a1.x; As[ac + 5][ar] = a1.y; As[ac + 6][ar] = a1.z; As[ac + 7][ar] = a1.w;
        f4 b0 = *(const f4*)(B + (size_t)(k0 + br) * N + col0 + bc);
        f4 b1 = *(const f4*)(B + (size_t)(k0 + br) * N + col0 + bc + 4);
        *(f4*)&Bs[br][bc] = b0; *(f4*)&Bs[br][bc + 4] = b1;
        __syncthreads();
#pragma unroll
        for (int kk = 0; kk < 16; ++kk) {
            float a[8], b[8];
            *(f4*)&a[0] = *(const f4*)&As[kk][ty * 8];
            *(f4*)&a[4] = *(const f4*)&As[kk][ty * 8 + 4];
            *(f4*)&b[0] = *(const f4*)&Bs[kk][tx * 8];
            *(f4*)&b[4] = *(const f4*)&Bs[kk][tx * 8 + 4];
#pragma unroll
            for (int i = 0; i < 8; ++i)
#pragma unroll
                for (int j = 0; j < 8; ++j) acc[i][j] = fmaf(a[i], b[j], acc[i][j]);
        }
        __syncthreads();
    }
#pragma unroll
    for (int i = 0; i < 8; ++i) {
        float* crow = C + (size_t)(row0 + ty * 8 + i) * N + col0 + tx * 8;
#pragma unroll
        for (int j = 0; j < 8; ++j) {
            float v = acc[i][j] + bias[col0 + tx * 8 + j];
            if (relu) v = fmaxf(v, 0.f);
            crow[j] = v;
        }
    }
}

// ---------------------------------------------------------------- CSR build
__global__ __launch_bounds__(256) void k_hist(const int* __restrict__ Wr, int* __restrict__ cnt)
{
    int e = blockIdx.x * 256 + threadIdx.x;
    if (e < EE) atomicAdd(&cnt[Wr[e]], 1);
}

__global__ __launch_bounds__(256) void k_scan1(const int* __restrict__ cnt,
    int* __restrict__ excl, int* __restrict__ bsum)
{
    __shared__ int s[256];
    int b = blockIdx.x, t = threadIdx.x;
    int v = cnt[b * 256 + t];
    s[t] = v; __syncthreads();
    for (int o = 1; o < 256; o <<= 1) {
        int x = (t >= o) ? s[t - o] : 0;
        __syncthreads();
        s[t] += x;
        __syncthreads();
    }
    excl[b * 256 + t] = s[t] - v;
    if (t == 255) bsum[b] = s[255];
}

__global__ void k_scan2(const int* __restrict__ bsum, int* __restrict__ boff)
{
    __shared__ int s[256];
    int t = threadIdx.x;
    int v = bsum[t]; s[t] = v; __syncthreads();
    for (int o = 1; o < 256; o <<= 1) {
        int x = (t >= o) ? s[t - o] : 0;
        __syncthreads();
        s[t] += x;
        __syncthreads();
    }
    boff[t] = s[t] - v;
}

__global__ __launch_bounds__(256) void k_scan3(const int* __restrict__ excl, const int* __restrict__ boff,
    int* __restrict__ rowptr, int* __restrict__ cursor)
{
    int i = blockIdx.x * 256 + threadIdx.x;
    int v = excl[i] + boff[i >> 8];
    rowptr[i] = v; cursor[i] = v;
    if (i == 0) rowptr[NN] = EE;
}

__global__ __launch_bounds__(256) void k_scatter(const int* __restrict__ Wr, const int* __restrict__ Wc,
    const float* __restrict__ Wv, int* __restrict__ cursor, int* __restrict__ ecol, float* __restrict__ ev)
{
    int e = blockIdx.x * 256 + threadIdx.x;
    if (e >= EE) return;
    int r = Wr[e];
    int p = atomicAdd(&cursor[r], 1);
    ecol[p] = Wc[e]; ev[p] = Wv[e];
}

// ---------------------------------------------------------------- SpMM (CSR, one wave per row, f32)
__global__ __launch_bounds__(256) void k_spmm_csr(const int* __restrict__ rowptr,
    const int* __restrict__ ecol, const float* __restrict__ eval,
    const float* __restrict__ X, float* __restrict__ Y)
{
    int row = blockIdx.x * 4 + (threadIdx.x >> 6);
    int lane = threadIdx.x & 63;
    int s = rowptr[row], e = rowptr[row + 1];
    float a0 = 0.f, a1 = 0.f;
    for (int i = s; i < e; ++i) {
        int cc = ecol[i];
        float w = eval[i];
        float2 x = *(const float2*)(X + (size_t)cc * D + lane * 2);
        a0 = fmaf(w, x.x, a0);
        a1 = fmaf(w, x.y, a1);
    }
    float2* yr = (float2*)(Y + (size_t)row * D + lane * 2);
    *yr = make_float2(a0, a1);
}

// ---------------------------------------------------------------- BN stats (f32 in, f64 partials, deterministic)
__global__ __launch_bounds__(128) void k_bnstats(const float* __restrict__ X,
    double* __restrict__ psum, double* __restrict__ pssq)
{
    int d = threadIdx.x;
    int r0 = blockIdx.x * 128;
    double s = 0.0, q = 0.0;
#pragma unroll 4
    for (int r = r0; r < r0 + 128; ++r) {
        double v = (double)X[(size_t)r * D + d];
        s += v; q = fma(v, v, q);
    }
    psum[blockIdx.x * 128 + d] = s;
    pssq[blockIdx.x * 128 + d] = q;
}

__global__ void k_bnfin(const double* __restrict__ psum, const double* __restrict__ pssq,
    const float* __restrict__ gamma, const float* __restrict__ beta,
    double* __restrict__ a, double* __restrict__ c, int nb, int layer)
{
    int t = threadIdx.x;
    if (t >= nb * 128) return;
    int blk = t >> 7, d = t & 127;
    const double* ps = psum + blk * 65536;
    const double* pq = pssq + blk * 65536;
    double s = 0.0, q = 0.0;
    for (int j = 0; j < 512; ++j) { s += ps[j * 128 + d]; q += pq[j * 128 + d]; }
    double m = s * (1.0 / 65536.0);
    double v = q * (1.0 / 65536.0) - m * m;
    double aa = (double)gamma[layer * 128 + d] / sqrt(v + 1e-5);
    a[t] = aa;
    c[t] = (double)beta[layer * 128 + d] - m * aa;
}

// ---------------------------------------------------------------- elementwise (f32, f4)
__global__ __launch_bounds__(256) void k_mean2(const f4* __restrict__ x0, const f4* __restrict__ x1,
                                               f4* __restrict__ o)
{
    int i = blockIdx.x * 256 + threadIdx.x;
    f4 a = x0[i], b = x1[i];
    f4 r;
    r.x = 0.5f * (a.x + b.x); r.y = 0.5f * (a.y + b.y);
    r.z = 0.5f * (a.z + b.z); r.w = 0.5f * (a.w + b.w);
    o[i] = r;
}

__global__ __launch_bounds__(256) void k_hidden(const f4* __restrict__ p0, const f4* __restrict__ p1,
    const double* __restrict__ a, const double* __restrict__ c, f4* __restrict__ o)
{
    int i = blockIdx.x * 256 + threadIdx.x;
    int d4 = (i & 31) * 4;
    f4 x = p0[i], y = p1[i];
    f4 r;
#pragma unroll
    for (int j = 0; j < 4; ++j) {
        float a0 = (float)a[d4 + j], c0 = (float)c[d4 + j];
        float a1 = (float)a[128 + d4 + j], c1 = (float)c[128 + d4 + j];
        float xv = (&x.x)[j], yv = (&y.x)[j];
        (&r.x)[j] = 0.5f * (fmaxf(fmaf(xv, a0, c0), 0.f) + fmaxf(fmaf(yv, a1, c1), 0.f));
    }
    o[i] = r;
}

__global__ __launch_bounds__(256) void k_bnapply(f4* __restrict__ H,
    const double* __restrict__ a, const double* __restrict__ c)
{
    int i = blockIdx.x * 256 + threadIdx.x;
    int d4 = (i & 31) * 4;
    f4 x = H[i];
#pragma unroll
    for (int j = 0; j < 4; ++j) {
        float a0 = (float)a[d4 + j], c0 = (float)c[d4 + j];
        (&x.x)[j] = fmaxf(fmaf((&x.x)[j], a0, c0), 0.f);
    }
    H[i] = x;
}

// ---------------------------------------------------------------- concat MLP (f32, 4 elems/thread)
__global__ __launch_bounds__(256) void k_concat(const f4* __restrict__ h0, const f4* __restrict__ h1,
    const f4* __restrict__ h2, const f4* __restrict__ h3,
    const float* __restrict__ w1, const float* __restrict__ b1,
    const float* __restrict__ w2, const float* __restrict__ b2,
    f4* __restrict__ Hpre)
{
    __shared__ float sw0[128], sw1_[128], sw2_[128], sw3[128], sv[128], sb[128];
    int t = threadIdx.x;
    if (t < 128) {
        sw0[t] = w1[t];        sw1_[t] = w1[128 + t];
        sw2_[t] = w1[256 + t]; sw3[t]  = w1[384 + t];
        sv[t]  = w2[t];        sb[t]   = b1[t];
    }
    __syncthreads();
    int i = blockIdx.x * 256 + t;  // f4 units, < N*D/4
    f4 x0 = h0[i], x1 = h1[i], x2 = h2[i], x3 = h3[i];
    float bb2 = b2[0];
    float acc0 = bb2, acc1 = bb2, acc2 = bb2, acc3 = bb2;
#pragma unroll 4
    for (int h = 0; h < D; ++h) {
        float w0 = sw0[h], ww1 = sw1_[h], ww2 = sw2_[h], w3 = sw3[h], bb = sb[h], vv = sv[h];
        float t0 = fmaf(x3.x, w3, fmaf(x2.x, ww2, fmaf(x1.x, ww1, fmaf(x0.x, w0, bb))));
        float t1 = fmaf(x3.y, w3, fmaf(x2.y, ww2, fmaf(x1.y, ww1, fmaf(x0.y, w0, bb))));
        float t2 = fmaf(x3.z, w3, fmaf(x2.z, ww2, fmaf(x1.z, ww1, fmaf(x0.z, w0, bb))));
        float t3 = fmaf(x3.w, w3, fmaf(x2.w, ww2, fmaf(x1.w, ww1, fmaf(x0.w, w0, bb))));
        acc0 = fmaf(fmaxf(t0, 0.f), vv, acc0);
        acc1 = fmaf(fmaxf(t1, 0.f), vv, acc1);
        acc2 = fmaf(fmaxf(t2, 0.f), vv, acc2);
        acc3 = fmaf(fmaxf(t3, 0.f), vv, acc3);
    }
    f4 r; r.x = acc0; r.y = acc1; r.z = acc2; r.w = acc3;
    Hpre[i] = r;
}

// ---------------------------------------------------------------- S = softmax(hid @ w2 + b2) (f32)
__global__ __launch_bounds__(256) void k_s(const float* __restrict__ hid,
    const float* __restrict__ w2, const float* __restrict__ b2, float* __restrict__ S)
{
    int n = blockIdx.x * 256 + threadIdx.x;
    if (n >= NN) return;
    const float* hr = hid + (size_t)n * D;
    float s[10];
#pragma unroll
    for (int k = 0; k < 10; ++k) s[k] = b2[k];
    for (int h = 0; h < D; h += 4) {
        f4 hv = *(const f4*)(hr + h);
#pragma unroll
        for (int k = 0; k < 10; ++k) {
            s[k] = fmaf(hv.x, w2[(h + 0) * 10 + k], s[k]);
            s[k] = fmaf(hv.y, w2[(h + 1) * 10 + k], s[k]);
            s[k] = fmaf(hv.z, w2[(h + 2) * 10 + k], s[k]);
            s[k] = fmaf(hv.w, w2[(h + 3) * 10 + k], s[k]);
        }
    }
    float m = s[0];
#pragma unroll
    for (int k = 1; k < 10; ++k) m = fmaxf(m, s[k]);
    float e[10], sum = 0.f;
#pragma unroll
    for (int k = 0; k < 10; ++k) { e[k] = expf(s[k] - m); sum += e[k]; }
    float inv = 1.f / sum;
#pragma unroll
    for (int k = 0; k < 10; ++k) S[(size_t)n * 10 + k] = e[k] * inv;
}

// ---------------------------------------------------------------- E_all (f32 in, f64 accum, dual store)
__global__ __launch_bounds__(256) void k_eall(const float* __restrict__ S, const float* __restrict__ H,
    const int* __restrict__ off, float* __restrict__ Eo, double* __restrict__ E64)
{
    int g = blockIdx.x;
    int d = threadIdx.x & 127;
    int half = threadIdx.x >> 7;
    double acc[5] = {0.0, 0.0, 0.0, 0.0, 0.0};
    int s0 = off[g], s1 = off[g + 1];
    for (int n = s0; n < s1; ++n) {
        double hv = (double)H[(size_t)n * D + d];
#pragma unroll
        for (int j = 0; j < 5; ++j) acc[j] = fma((double)S[(size_t)n * 10 + half * 5 + j], hv, acc[j]);
    }
#pragma unroll
    for (int j = 0; j < 5; ++j) {
        size_t o = (size_t)g * 1280 + (half * 5 + j) * D + d;
        Eo[o] = (float)acc[j];
        E64[o] = acc[j];
    }
}

// ---------------------------------------------------------------- graph offsets
__global__ void k_off(const int* __restrict__ gi, int* __restrict__ off)
{
    int g = blockIdx.x * 256 + threadIdx.x;
    if (g > GG) return;
    int lo = 0, hi = NN;
    while (lo < hi) { int mid = (lo + hi) >> 1; if (gi[mid] < g) lo = mid + 1; else hi = mid; }
    off[g] = lo;
}

// ---------------------------------------------------------------- corr
__global__ void k_corr(const float* __restrict__ ci, const float* __restrict__ ca, float* __restrict__ corr)
{
    int t = threadIdx.x;
    if (t >= 160) return;
    int r = t / 16, c = t % 16;
    double m = -1e300;
    for (int i = 0; i < 10; ++i) m = fmax(m, (double)ci[i * 16 + c]);
    double s = 0.0;
    for (int i = 0; i < 10; ++i) s += exp((double)ci[i * 16 + c] - m);
    double vi = exp((double)ci[r * 16 + c] - m) / s;
    double m2 = -1e300;
    for (int j = 0; j < 16; ++j) m2 = fmax(m2, (double)ca[r * 16 + j]);
    double s2 = 0.0;
    for (int j = 0; j < 16; ++j) s2 += exp((double)ca[r * 16 + j] - m2);
    double va = exp((double)ca[r * 16 + c] - m2) / s2;
    corr[t] = (float)(vi * va);
}

// ---------------------------------------------------------------- JAX threefry gumbel — PARTITIONABLE (verified)
__device__ __forceinline__ unsigned tf_rotl(unsigned x, unsigned n) { return (x << n) | (x >> (32u - n)); }

__global__ void k_gumbel(double* __restrict__ out)
{
    int i = blockIdx.x * 256 + threadIdx.x;
    if (i >= 5120) return;
    unsigned x0 = 0u;              // hi32 of 64-bit counter
    unsigned x1 = (unsigned)i;     // lo32
    const unsigned ks0 = 0u, ks1 = 42u;
    const unsigned ks2 = 0x1BD11BDAu ^ ks0 ^ ks1;
    x0 += ks0; x1 += ks1;
#define TF_ROUND(rr) { x0 += x1; x1 = tf_rotl(x1, rr); x1 ^= x0; }
    TF_ROUND(13) TF_ROUND(15) TF_ROUND(26) TF_ROUND(6)
    x0 += ks1; x1 += ks2 + 1u;
    TF_ROUND(17) TF_ROUND(29) TF_ROUND(16) TF_ROUND(24)
    x0 += ks2; x1 += ks0 + 2u;
    TF_ROUND(13) TF_ROUND(15) TF_ROUND(26) TF_ROUND(6)
    x0 += ks0; x1 += ks1 + 3u;
    TF_ROUND(17) TF_ROUND(29) TF_ROUND(16) TF_ROUND(24)
    x0 += ks1; x1 += ks2 + 4u;
    TF_ROUND(13) TF_ROUND(15) TF_ROUND(26) TF_ROUND(6)
    x0 += ks2; x1 += ks0 + 5u;
#undef TF_ROUND
    unsigned bits = x0 ^ x1;       // partitionable 32-bit combine
    unsigned fb = (bits >> 9) | 0x3f800000u;
    float f = __uint_as_float(fb) - 1.0f;
    const float tinyf = 1.1754943508222875e-38f;
    float u32v = fmaxf(tinyf, f * (1.0f - tinyf) + tinyf);
    out[i] = -log(-log((double)u32v));
}

// ---------------------------------------------------------------- pred1 + sampling (f64)
__global__ __launch_bounds__(64) void k_pred1(const double* __restrict__ E64, const float* __restrict__ fw,
    const float* __restrict__ fb, const double* __restrict__ gum, const int* __restrict__ tgt,
    const float* __restrict__ corr, float* __restrict__ pred1, float* __restrict__ ind,
    float* __restrict__ cmask)
{
    int g = blockIdx.x;
    int l = threadIdx.x;
    double acc[10];
#pragma unroll
    for (int c = 0; c < 10; ++c) acc[c] = 0.0;
    for (int i = l; i < 1280; i += 64) {
        double e = E64[(size_t)g * 1280 + i];
#pragma unroll
        for (int c = 0; c < 10; ++c) acc[c] = fma(e, (double)fw[i * 10 + c], acc[c]);
    }
#pragma unroll
    for (int c = 0; c < 10; ++c) {
        double v = acc[c];
        for (int o = 32; o > 0; o >>= 1) v += __shfl_down(v, o, 64);
        acc[c] = v;
    }
    if (l == 0) {
        double best = -1e300; int bi = 0;
        for (int c = 0; c < 10; ++c) {
            double p = acc[c] + (double)fb[c];
            pred1[g * 10 + c] = (float)p;
            double y = p + gum[g * 10 + c];
            if (y > best) { best = y; bi = c; }
        }
        ind[g] = (bi == tgt[g]) ? 1.f : 0.f;
        for (int f = 0; f < 16; ++f) cmask[g * 16 + f] = corr[bi * 16 + f];
    }
}

// ---------------------------------------------------------------- Q + feature_mask (f32)
__global__ __launch_bounds__(128) void k_q(const float* __restrict__ Eo, const float* __restrict__ w1,
    const float* __restrict__ b1, const float* __restrict__ w2, const float* __restrict__ b2,
    const float* __restrict__ cmask, float* __restrict__ Q, float* __restrict__ fm)
{
    int gk = blockIdx.x;
    int g = gk / 10;
    int h = threadIdx.x;
    __shared__ float e[128];
    __shared__ float hh[128];
    __shared__ float qv[16];
    __shared__ float pr[16];
    e[h] = Eo[(size_t)gk * D + h];
    __syncthreads();
    float acc = b1[h];
#pragma unroll 8
    for (int d = 0; d < D; ++d) acc = fmaf(e[d], w1[d * D + h], acc);
    hh[h] = fmaxf(acc, 0.f);
    __syncthreads();
    if (h < 16) {
        float s = b2[h];
        for (int d = 0; d < D; ++d) s = fmaf(hh[d], w2[d * 16 + h], s);
        qv[h] = s;
    }
    __syncthreads();
    if (h < 16) {
        float m = qv[0];
        for (int f = 1; f < 16; ++f) m = fmaxf(m, qv[f]);
        pr[h] = expf(qv[h] - m);
    }
    __syncthreads();
    if (h < 16) {
        float s = 0.f;
        for (int f = 0; f < 16; ++f) s += pr[f];
        float q = pr[h] / s;
        Q[(size_t)gk * 16 + h] = q;
        qv[h] = q * cmask[g * 16 + h];
    }
    __syncthreads();
    if (h == 0) {
        float s = 0.f;
        for (int f = 0; f < 16; ++f) s += qv[f];
        fm[gk] = s;
    }
}

// ---------------------------------------------------------------- pred2 (f64 accum from E64)
__global__ __launch_bounds__(64) void k_pred2(const double* __restrict__ E64, const float* __restrict__ fw,
    const float* __restrict__ fb, const float* __restrict__ fm, float* __restrict__ pred2)
{
    int g = blockIdx.x;
    int l = threadIdx.x;
    double acc[10];
#pragma unroll
    for (int c = 0; c < 10; ++c) acc[c] = 0.0;
    for (int i = l; i < 1280; i += 64) {
        int k = i >> 7;
        double e = E64[(size_t)g * 1280 + i] * (double)fm[g * 10 + k];
#pragma unroll
        for (int c = 0; c < 10; ++c) acc[c] = fma(e, (double)fw[i * 10 + c], acc[c]);
    }
#pragma unroll
    for (int c = 0; c < 10; ++c) {
        double v = acc[c];
        for (int o = 32; o > 0; o >>= 1) v += __shfl_down(v, o, 64);
        acc[c] = v;
    }
    if (l == 0)
        for (int c = 0; c < 10; ++c) pred2[g * 10 + c] = (float)(acc[c] + (double)fb[c]);
}

// ================================================================ host
extern "C" void kernel_launch(void* const* d_in, const int* in_sizes, int n_in,
                              void* d_out, int out_size, void* d_ws, size_t ws_size,
                              hipStream_t stream)
{
    const float* features = (const float*)d_in[0];
    const int*   W_row    = (const int*)d_in[1];
    const int*   W_col    = (const int*)d_in[2];
    const float* W_vals   = (const float*)d_in[3];
    const int*   gi       = (const int*)d_in[4];
    const int*   targets  = (const int*)d_in[5];
    const float* enc_w1   = (const float*)d_in[6];
    const float* enc_b1   = (const float*)d_in[7];
    const float* enc_w2   = (const float*)d_in[8];
    const float* enc_b2   = (const float*)d_in[9];
    const float* bn_gamma = (const float*)d_in[10];
    const float* bn_beta  = (const float*)d_in[11];
    const float* concat_w1= (const float*)d_in[12];
    const float* concat_b1= (const float*)d_in[13];
    const float* concat_w2= (const float*)d_in[14];
    const float* concat_b2= (const float*)d_in[15];
    const float* smlp_w1  = (const float*)d_in[16];
    const float* smlp_b1  = (const float*)d_in[17];
    const float* smlp_w2  = (const float*)d_in[18];
    const float* smlp_b2  = (const float*)d_in[19];
    const float* proto_w1 = (const float*)d_in[20];
    const float* proto_b1 = (const float*)d_in[21];
    const float* proto_w2 = (const float*)d_in[22];
    const float* proto_b2 = (const float*)d_in[23];
    const float* final_w  = (const float*)d_in[24];
    const float* final_b  = (const float*)d_in[25];
    const float* corr_i   = (const float*)d_in[26];
    const float* corr_a   = (const float*)d_in[27];

    float* out = (float*)d_out;
    float* o_pred1 = out + 0;
    float* o_pred2 = out + 5120;
    float* o_S     = out + 10240;
    float* o_H     = out + 665600;
    float* o_ind   = out + 9054208;
    float* o_E     = out + 9054720;
    float* o_Q     = out + 9710080;

    // ---------------- workspace arena
    char* base = (char*)d_ws;
    size_t off = 0;
    auto alloc = [&](size_t n) -> char* {
        char* r = base + off;
        off = (off + n + 255) & ~(size_t)255;
        return r;
    };
    int*    d_off   = (int*)alloc(513 * 4);
    double* d_a     = (double*)alloc(256 * 8);
    double* d_c     = (double*)alloc(256 * 8);
    double* d_gum   = (double*)alloc(5120 * 8);
    float*  d_corr  = (float*)alloc(160 * 4);
    float*  d_cmask = (float*)alloc(512 * 16 * 4);
    float*  d_fm    = (float*)alloc(5120 * 4);
    double* psum    = (double*)alloc(2 * 512 * 128 * 8);
    double* pssq    = (double*)alloc(2 * 512 * 128 * 8);
    int*    cnt     = (int*)alloc((size_t)NN * 4);
    int*    excl    = (int*)alloc((size_t)NN * 4);
    int*    bsum    = (int*)alloc(256 * 4);
    int*    boff    = (int*)alloc(256 * 4);
    int*    rowptr  = (int*)alloc((size_t)(NN + 1) * 4);
    int*    cursor  = (int*)alloc((size_t)NN * 4);
    int*    ecol    = (int*)alloc((size_t)EE * 4);
    float*  evalv   = (float*)alloc((size_t)EE * 4);
    double* E64     = (double*)alloc((size_t)GG * 1280 * 8);   // 5.24 MB

    const size_t SZ = (size_t)NN * D * 4;   // 32 MiB per f32 tensor
    float* rot0 = (float*)alloc(SZ);
    float* rot1 = (float*)alloc(SZ);
    float* rot2 = (float*)alloc(SZ);
    float* h0   = (float*)alloc(SZ);
    float* h1   = (float*)alloc(SZ);
    float* h2   = (float*)alloc(SZ);
    float* h3   = (float*)alloc(SZ);
    float* Tenc = h0;        // N x 256 f32 spans h0+h1; both dead until mean2/k_hidden write them
    float* hid2 = rot0;      // smlp hidden reuses rot region after prop loop

    // ---------------- small precomputations
    k_off   <<<3, 256, 0, stream>>>(gi, d_off);
    k_corr  <<<1, 256, 0, stream>>>(corr_i, corr_a, d_corr);
    k_gumbel<<<20, 256, 0, stream>>>(d_gum);

    // ---------------- CSR build
    hipMemsetAsync(cnt, 0, (size_t)NN * 4, stream);
    k_hist   <<<EE / 256, 256, 0, stream>>>(W_row, cnt);
    k_scan1  <<<256, 256, 0, stream>>>(cnt, excl, bsum);
    k_scan2  <<<1, 256, 0, stream>>>(bsum, boff);
    k_scan3  <<<256, 256, 0, stream>>>(excl, boff, rowptr, cursor);
    k_scatter<<<EE / 256, 256, 0, stream>>>(W_row, W_col, W_vals, cursor, ecol, evalv);

    // ---------------- encoder (f32)
    k_gemm<<<dim3(2, 512), 256, 0, stream>>>(features, enc_w1,             enc_b1,       Tenc, NN, 256, 128, 1);
    k_gemm<<<dim3(1, 512), 256, 0, stream>>>(Tenc,     enc_w2,             enc_b2,       rot0, NN, 128, 256, 0);
    k_gemm<<<dim3(2, 512), 256, 0, stream>>>(features, enc_w1 + 128 * 256, enc_b1 + 256, Tenc, NN, 256, 128, 1);
    k_gemm<<<dim3(1, 512), 256, 0, stream>>>(Tenc,     enc_w2 + 256 * 128, enc_b2 + 128, rot1, NN, 128, 256, 0);
    k_mean2<<<8192, 256, 0, stream>>>((const f4*)rot0, (const f4*)rot1, (f4*)h0);

    // ---------------- propagation loop
    float* cur0 = rot0;
    float* cur1 = rot1;
    float* fre  = rot2;
    float* hbuf[4] = { h0, h1, h2, h3 };
    for (int p = 0; p < 3; ++p) {
        k_spmm_csr<<<NN / 4, 256, 0, stream>>>(rowptr, ecol, evalv, cur0, fre);
        k_spmm_csr<<<NN / 4, 256, 0, stream>>>(rowptr, ecol, evalv, cur1, cur0);
        k_bnstats<<<512, 128, 0, stream>>>(fre,  psum,         pssq);
        k_bnstats<<<512, 128, 0, stream>>>(cur0, psum + 65536, pssq + 65536);
        k_bnfin<<<1, 256, 0, stream>>>(psum, pssq, bn_gamma, bn_beta, d_a, d_c, 2, p);
        k_hidden<<<8192, 256, 0, stream>>>((const f4*)fre, (const f4*)cur0, d_a, d_c, (f4*)hbuf[1 + p]);
        float* t0 = fre; float* t1 = cur0; float* t2 = cur1;
        cur0 = t0; cur1 = t1; fre = t2;
    }

    // ---------------- concat MLP -> o_H, BN+relu in place
    k_concat<<<8192, 256, 0, stream>>>((const f4*)h0, (const f4*)h1, (const f4*)h2, (const f4*)h3,
                                       concat_w1, concat_b1, concat_w2, concat_b2, (f4*)o_H);
    k_bnstats<<<512, 128, 0, stream>>>(o_H, psum, pssq);
    k_bnfin<<<1, 256, 0, stream>>>(psum, pssq, bn_gamma, bn_beta, d_a, d_c, 1, 3);
    k_bnapply<<<8192, 256, 0, stream>>>((f4*)o_H, d_a, d_c);

    // ---------------- S_all
    k_gemm<<<dim3(1, 512), 256, 0, stream>>>(o_H, smlp_w1, smlp_b1, hid2, NN, 128, 128, 1);
    k_s<<<256, 256, 0, stream>>>(hid2, smlp_w2, smlp_b2, o_S);

    // ---------------- E_all, heads
    k_eall <<<512, 256, 0, stream>>>(o_S, o_H, d_off, o_E, E64);
    k_pred1<<<512, 64, 0, stream>>>(E64, final_w, final_b, d_gum, targets, d_corr,
                                    o_pred1, o_ind, d_cmask);
    k_q    <<<5120, 128, 0, stream>>>(o_E, proto_w1, proto_b1, proto_w2, proto_b2,
                                      d_cmask, o_Q, d_fm);
    k_pred2<<<512, 64, 0, stream>>>(E64, final_w, final_b, d_fm, o_pred2);

    (void)in_sizes; (void)n_in; (void)out_size; (void)ws_size;
}

// Round 7
// 1342.302 us; speedup vs baseline: 1.5290x; 1.1853x over previous
//
#include <hip/hip_runtime.h>
#include <math.h>

#define NN 65536
#define EE 1048576
#define GG 512
#define D  128

typedef float4 f4;

// ---------------------------------------------------------------- GEMM (fp32, 128x128 tile, 8x8 micro, reg-prefetch pipeline)
// C[M,N] = act(A[M,K] @ B[K,N] + bias[N]); M%128==0, N%128==0, K%16==0
__global__ __launch_bounds__(256) void k_gemm(const float* __restrict__ A,
    const float* __restrict__ B, const float* __restrict__ bias,
    float* __restrict__ C, int M, int N, int K, int relu)
{
    __shared__ __align__(16) float As[16][132];
    __shared__ __align__(16) float Bs[16][132];
    int tid = threadIdx.x;
    int tx = tid & 15, ty = tid >> 4;
    int row0 = blockIdx.y * 128, col0 = blockIdx.x * 128;
    float acc[8][8];
#pragma unroll
    for (int i = 0; i < 8; ++i)
#pragma unroll
        for (int j = 0; j < 8; ++j) acc[i][j] = 0.f;
    int ar = tid >> 1, ac = (tid & 1) * 8;
    int br = tid >> 4, bc = (tid & 15) * 8;
    const float* aptr = A + (size_t)(row0 + ar) * K + ac;
    const float* bptr = B + (size_t)br * N + col0 + bc;

    // preload tile 0
    f4 pa0 = *(const f4*)(aptr);
    f4 pa1 = *(const f4*)(aptr + 4);
    f4 pb0 = *(const f4*)(bptr);
    f4 pb1 = *(const f4*)(bptr + 4);

    for (int k0 = 0; k0 < K; k0 += 16) {
        // store current prefetched tile to LDS
        As[ac + 0][ar] = pa0.x; As[ac + 1][ar] = pa0.y; As[ac + 2][ar] = pa0.z; As[ac + 3][ar] = pa0.w;
        As[ac + 4][ar] = pa1.x; As[ac + 5][ar] = pa1.y; As[ac + 6][ar] = pa1.z; As[ac + 7][ar] = pa1.w;
        *(f4*)&Bs[br][bc] = pb0; *(f4*)&Bs[br][bc + 4] = pb1;
        __syncthreads();
        // issue next tile's global loads (overlap with compute below)
        if (k0 + 16 < K) {
            pa0 = *(const f4*)(aptr + k0 + 16);
            pa1 = *(const f4*)(aptr + k0 + 16 + 4);
            pb0 = *(const f4*)(bptr + (size_t)(k0 + 16) * N);
            pb1 = *(const f4*)(bptr + (size_t)(k0 + 16) * N + 4);
        }
#pragma unroll
        for (int kk = 0; kk < 16; ++kk) {
            float a[8], b[8];
            *(f4*)&a[0] = *(const f4*)&As[kk][ty * 8];
            *(f4*)&a[4] = *(const f4*)&As[kk][ty * 8 + 4];
            *(f4*)&b[0] = *(const f4*)&Bs[kk][tx * 8];
            *(f4*)&b[4] = *(const f4*)&Bs[kk][tx * 8 + 4];
#pragma unroll
            for (int i = 0; i < 8; ++i)
#pragma unroll
                for (int j = 0; j < 8; ++j) acc[i][j] = fmaf(a[i], b[j], acc[i][j]);
        }
        __syncthreads();
    }
#pragma unroll
    for (int i = 0; i < 8; ++i) {
        float* crow = C + (size_t)(row0 + ty * 8 + i) * N + col0 + tx * 8;
#pragma unroll
        for (int j = 0; j < 8; ++j) {
            float v = acc[i][j] + bias[col0 + tx * 8 + j];
            if (relu) v = fmaxf(v, 0.f);
            crow[j] = v;
        }
    }
}

// ---------------------------------------------------------------- CSR build
__global__ __launch_bounds__(256) void k_hist(const int* __restrict__ Wr, int* __restrict__ cnt)
{
    int e = blockIdx.x * 256 + threadIdx.x;
    if (e < EE) atomicAdd(&cnt[Wr[e]], 1);
}

__global__ __launch_bounds__(256) void k_scan1(const int* __restrict__ cnt,
    int* __restrict__ excl, int* __restrict__ bsum)
{
    __shared__ int s[256];
    int b = blockIdx.x, t = threadIdx.x;
    int v = cnt[b * 256 + t];
    s[t] = v; __syncthreads();
    for (int o = 1; o < 256; o <<= 1) {
        int x = (t >= o) ? s[t - o] : 0;
        __syncthreads();
        s[t] += x;
        __syncthreads();
    }
    excl[b * 256 + t] = s[t] - v;
    if (t == 255) bsum[b] = s[255];
}

__global__ void k_scan2(const int* __restrict__ bsum, int* __restrict__ boff)
{
    __shared__ int s[256];
    int t = threadIdx.x;
    int v = bsum[t]; s[t] = v; __syncthreads();
    for (int o = 1; o < 256; o <<= 1) {
        int x = (t >= o) ? s[t - o] : 0;
        __syncthreads();
        s[t] += x;
        __syncthreads();
    }
    boff[t] = s[t] - v;
}

__global__ __launch_bounds__(256) void k_scan3(const int* __restrict__ excl, const int* __restrict__ boff,
    int* __restrict__ rowptr, int* __restrict__ cursor)
{
    int i = blockIdx.x * 256 + threadIdx.x;
    int v = excl[i] + boff[i >> 8];
    rowptr[i] = v; cursor[i] = v;
    if (i == 0) rowptr[NN] = EE;
}

__global__ __launch_bounds__(256) void k_scatter(const int* __restrict__ Wr, const int* __restrict__ Wc,
    const float* __restrict__ Wv, int* __restrict__ cursor, int* __restrict__ ecol, float* __restrict__ ev)
{
    int e = blockIdx.x * 256 + threadIdx.x;
    if (e >= EE) return;
    int r = Wr[e];
    int p = atomicAdd(&cursor[r], 1);
    ecol[p] = Wc[e]; ev[p] = Wv[e];
}

// ---------------------------------------------------------------- SpMM (CSR, wave/row, 4-edge chunks)
// NOTE: launched as two SEQUENTIAL dispatches per propagation step; fusing
// them raced (round 6: Y of one half aliased X of the other). G16.
__global__ __launch_bounds__(256) void k_spmm(const int* __restrict__ rowptr,
    const int* __restrict__ ecol, const float* __restrict__ eval,
    const float* __restrict__ X, float* __restrict__ Y)
{
    int row = blockIdx.x * 4 + (threadIdx.x >> 6);
    int lane = threadIdx.x & 63;
    int s = rowptr[row], e = rowptr[row + 1];
    float a0 = 0.f, a1 = 0.f;
    int i = s;
    for (; i + 4 <= e; i += 4) {
        int   c0 = ecol[i], c1 = ecol[i + 1], c2 = ecol[i + 2], c3 = ecol[i + 3];
        float w0 = eval[i], w1 = eval[i + 1], w2 = eval[i + 2], w3 = eval[i + 3];
        float2 x0 = *(const float2*)(X + (size_t)c0 * D + lane * 2);
        float2 x1 = *(const float2*)(X + (size_t)c1 * D + lane * 2);
        float2 x2 = *(const float2*)(X + (size_t)c2 * D + lane * 2);
        float2 x3 = *(const float2*)(X + (size_t)c3 * D + lane * 2);
        a0 = fmaf(w0, x0.x, a0); a1 = fmaf(w0, x0.y, a1);
        a0 = fmaf(w1, x1.x, a0); a1 = fmaf(w1, x1.y, a1);
        a0 = fmaf(w2, x2.x, a0); a1 = fmaf(w2, x2.y, a1);
        a0 = fmaf(w3, x3.x, a0); a1 = fmaf(w3, x3.y, a1);
    }
    for (; i < e; ++i) {
        int cc = ecol[i];
        float w = eval[i];
        float2 x = *(const float2*)(X + (size_t)cc * D + lane * 2);
        a0 = fmaf(w, x.x, a0);
        a1 = fmaf(w, x.y, a1);
    }
    *(float2*)(Y + (size_t)row * D + lane * 2) = make_float2(a0, a1);
}

// ---------------------------------------------------------------- BN stats (dual matrix read-only fuse, f64 partials)
__global__ __launch_bounds__(128) void k_bnstats2(const float* __restrict__ X0, const float* __restrict__ X1,
    double* __restrict__ psum, double* __restrict__ pssq)
{
    const float* __restrict__ X = blockIdx.y ? X1 : X0;
    int d = threadIdx.x;
    int r0 = blockIdx.x * 128;
    double s = 0.0, q = 0.0;
#pragma unroll 4
    for (int r = r0; r < r0 + 128; ++r) {
        double v = (double)X[(size_t)r * D + d];
        s += v; q = fma(v, v, q);
    }
    psum[blockIdx.y * 65536 + blockIdx.x * 128 + d] = s;
    pssq[blockIdx.y * 65536 + blockIdx.x * 128 + d] = q;
}

__global__ void k_bnfin(const double* __restrict__ psum, const double* __restrict__ pssq,
    const float* __restrict__ gamma, const float* __restrict__ beta,
    double* __restrict__ a, double* __restrict__ c, int nb, int layer)
{
    int t = threadIdx.x;
    if (t >= nb * 128) return;
    int blk = t >> 7, d = t & 127;
    const double* ps = psum + blk * 65536;
    const double* pq = pssq + blk * 65536;
    double s = 0.0, q = 0.0;
    for (int j = 0; j < 512; ++j) { s += ps[j * 128 + d]; q += pq[j * 128 + d]; }
    double m = s * (1.0 / 65536.0);
    double v = q * (1.0 / 65536.0) - m * m;
    double aa = (double)gamma[layer * 128 + d] / sqrt(v + 1e-5);
    a[t] = aa;
    c[t] = (double)beta[layer * 128 + d] - m * aa;
}

// ---------------------------------------------------------------- elementwise (f32, f4)
__global__ __launch_bounds__(256) void k_mean2(const f4* __restrict__ x0, const f4* __restrict__ x1,
                                               f4* __restrict__ o)
{
    int i = blockIdx.x * 256 + threadIdx.x;
    f4 a = x0[i], b = x1[i];
    f4 r;
    r.x = 0.5f * (a.x + b.x); r.y = 0.5f * (a.y + b.y);
    r.z = 0.5f * (a.z + b.z); r.w = 0.5f * (a.w + b.w);
    o[i] = r;
}

__global__ __launch_bounds__(256) void k_hidden(const f4* __restrict__ p0, const f4* __restrict__ p1,
    const double* __restrict__ a, const double* __restrict__ c, f4* __restrict__ o)
{
    int i = blockIdx.x * 256 + threadIdx.x;
    int d4 = (i & 31) * 4;
    f4 x = p0[i], y = p1[i];
    f4 r;
#pragma unroll
    for (int j = 0; j < 4; ++j) {
        float a0 = (float)a[d4 + j], c0 = (float)c[d4 + j];
        float a1 = (float)a[128 + d4 + j], c1 = (float)c[128 + d4 + j];
        float xv = (&x.x)[j], yv = (&y.x)[j];
        (&r.x)[j] = 0.5f * (fmaxf(fmaf(xv, a0, c0), 0.f) + fmaxf(fmaf(yv, a1, c1), 0.f));
    }
    o[i] = r;
}

__global__ __launch_bounds__(256) void k_bnapply(f4* __restrict__ H,
    const double* __restrict__ a, const double* __restrict__ c)
{
    int i = blockIdx.x * 256 + threadIdx.x;
    int d4 = (i & 31) * 4;
    f4 x = H[i];
#pragma unroll
    for (int j = 0; j < 4; ++j) {
        float a0 = (float)a[d4 + j], c0 = (float)c[d4 + j];
        (&x.x)[j] = fmaxf(fmaf((&x.x)[j], a0, c0), 0.f);
    }
    H[i] = x;
}

// ---------------------------------------------------------------- concat MLP (f32, 4 elems/thread)
__global__ __launch_bounds__(256) void k_concat(const f4* __restrict__ h0, const f4* __restrict__ h1,
    const f4* __restrict__ h2, const f4* __restrict__ h3,
    const float* __restrict__ w1, const float* __restrict__ b1,
    const float* __restrict__ w2, const float* __restrict__ b2,
    f4* __restrict__ Hpre)
{
    __shared__ float sw0[128], sw1_[128], sw2_[128], sw3[128], sv[128], sb[128];
    int t = threadIdx.x;
    if (t < 128) {
        sw0[t] = w1[t];        sw1_[t] = w1[128 + t];
        sw2_[t] = w1[256 + t]; sw3[t]  = w1[384 + t];
        sv[t]  = w2[t];        sb[t]   = b1[t];
    }
    __syncthreads();
    int i = blockIdx.x * 256 + t;  // f4 units, < N*D/4
    f4 x0 = h0[i], x1 = h1[i], x2 = h2[i], x3 = h3[i];
    float bb2 = b2[0];
    float acc0 = bb2, acc1 = bb2, acc2 = bb2, acc3 = bb2;
#pragma unroll 4
    for (int h = 0; h < D; ++h) {
        float w0 = sw0[h], ww1 = sw1_[h], ww2 = sw2_[h], w3 = sw3[h], bb = sb[h], vv = sv[h];
        float t0 = fmaf(x3.x, w3, fmaf(x2.x, ww2, fmaf(x1.x, ww1, fmaf(x0.x, w0, bb))));
        float t1 = fmaf(x3.y, w3, fmaf(x2.y, ww2, fmaf(x1.y, ww1, fmaf(x0.y, w0, bb))));
        float t2 = fmaf(x3.z, w3, fmaf(x2.z, ww2, fmaf(x1.z, ww1, fmaf(x0.z, w0, bb))));
        float t3 = fmaf(x3.w, w3, fmaf(x2.w, ww2, fmaf(x1.w, ww1, fmaf(x0.w, w0, bb))));
        acc0 = fmaf(fmaxf(t0, 0.f), vv, acc0);
        acc1 = fmaf(fmaxf(t1, 0.f), vv, acc1);
        acc2 = fmaf(fmaxf(t2, 0.f), vv, acc2);
        acc3 = fmaf(fmaxf(t3, 0.f), vv, acc3);
    }
    f4 r; r.x = acc0; r.y = acc1; r.z = acc2; r.w = acc3;
    Hpre[i] = r;
}

// ---------------------------------------------------------------- S = softmax(hid @ w2 + b2) (f32)
__global__ __launch_bounds__(256) void k_s(const float* __restrict__ hid,
    const float* __restrict__ w2, const float* __restrict__ b2, float* __restrict__ S)
{
    int n = blockIdx.x * 256 + threadIdx.x;
    if (n >= NN) return;
    const float* hr = hid + (size_t)n * D;
    float s[10];
#pragma unroll
    for (int k = 0; k < 10; ++k) s[k] = b2[k];
    for (int h = 0; h < D; h += 4) {
        f4 hv = *(const f4*)(hr + h);
#pragma unroll
        for (int k = 0; k < 10; ++k) {
            s[k] = fmaf(hv.x, w2[(h + 0) * 10 + k], s[k]);
            s[k] = fmaf(hv.y, w2[(h + 1) * 10 + k], s[k]);
            s[k] = fmaf(hv.z, w2[(h + 2) * 10 + k], s[k]);
            s[k] = fmaf(hv.w, w2[(h + 3) * 10 + k], s[k]);
        }
    }
    float m = s[0];
#pragma unroll
    for (int k = 1; k < 10; ++k) m = fmaxf(m, s[k]);
    float e[10], sum = 0.f;
#pragma unroll
    for (int k = 0; k < 10; ++k) { e[k] = expf(s[k] - m); sum += e[k]; }
    float inv = 1.f / sum;
#pragma unroll
    for (int k = 0; k < 10; ++k) S[(size_t)n * 10 + k] = e[k] * inv;
}

// ---------------------------------------------------------------- E_all (f32 in, f64 accum, dual store)
__global__ __launch_bounds__(256) void k_eall(const float* __restrict__ S, const float* __restrict__ H,
    const int* __restrict__ off, float* __restrict__ Eo, double* __restrict__ E64)
{
    int g = blockIdx.x;
    int d = threadIdx.x & 127;
    int half = threadIdx.x >> 7;
    double acc[5] = {0.0, 0.0, 0.0, 0.0, 0.0};
    int s0 = off[g], s1 = off[g + 1];
    for (int n = s0; n < s1; ++n) {
        double hv = (double)H[(size_t)n * D + d];
#pragma unroll
        for (int j = 0; j < 5; ++j) acc[j] = fma((double)S[(size_t)n * 10 + half * 5 + j], hv, acc[j]);
    }
#pragma unroll
    for (int j = 0; j < 5; ++j) {
        size_t o = (size_t)g * 1280 + (half * 5 + j) * D + d;
        Eo[o] = (float)acc[j];
        E64[o] = acc[j];
    }
}

// ---------------------------------------------------------------- graph offsets
__global__ void k_off(const int* __restrict__ gi, int* __restrict__ off)
{
    int g = blockIdx.x * 256 + threadIdx.x;
    if (g > GG) return;
    int lo = 0, hi = NN;
    while (lo < hi) { int mid = (lo + hi) >> 1; if (gi[mid] < g) lo = mid + 1; else hi = mid; }
    off[g] = lo;
}

// ---------------------------------------------------------------- corr
__global__ void k_corr(const float* __restrict__ ci, const float* __restrict__ ca, float* __restrict__ corr)
{
    int t = threadIdx.x;
    if (t >= 160) return;
    int r = t / 16, c = t % 16;
    double m = -1e300;
    for (int i = 0; i < 10; ++i) m = fmax(m, (double)ci[i * 16 + c]);
    double s = 0.0;
    for (int i = 0; i < 10; ++i) s += exp((double)ci[i * 16 + c] - m);
    double vi = exp((double)ci[r * 16 + c] - m) / s;
    double m2 = -1e300;
    for (int j = 0; j < 16; ++j) m2 = fmax(m2, (double)ca[r * 16 + j]);
    double s2 = 0.0;
    for (int j = 0; j < 16; ++j) s2 += exp((double)ca[r * 16 + j] - m2);
    double va = exp((double)ca[r * 16 + c] - m2) / s2;
    corr[t] = (float)(vi * va);
}

// ---------------------------------------------------------------- JAX threefry gumbel — PARTITIONABLE (verified)
__device__ __forceinline__ unsigned tf_rotl(unsigned x, unsigned n) { return (x << n) | (x >> (32u - n)); }

__global__ void k_gumbel(double* __restrict__ out)
{
    int i = blockIdx.x * 256 + threadIdx.x;
    if (i >= 5120) return;
    unsigned x0 = 0u;              // hi32 of 64-bit counter
    unsigned x1 = (unsigned)i;     // lo32
    const unsigned ks0 = 0u, ks1 = 42u;
    const unsigned ks2 = 0x1BD11BDAu ^ ks0 ^ ks1;
    x0 += ks0; x1 += ks1;
#define TF_ROUND(rr) { x0 += x1; x1 = tf_rotl(x1, rr); x1 ^= x0; }
    TF_ROUND(13) TF_ROUND(15) TF_ROUND(26) TF_ROUND(6)
    x0 += ks1; x1 += ks2 + 1u;
    TF_ROUND(17) TF_ROUND(29) TF_ROUND(16) TF_ROUND(24)
    x0 += ks2; x1 += ks0 + 2u;
    TF_ROUND(13) TF_ROUND(15) TF_ROUND(26) TF_ROUND(6)
    x0 += ks0; x1 += ks1 + 3u;
    TF_ROUND(17) TF_ROUND(29) TF_ROUND(16) TF_ROUND(24)
    x0 += ks1; x1 += ks2 + 4u;
    TF_ROUND(13) TF_ROUND(15) TF_ROUND(26) TF_ROUND(6)
    x0 += ks2; x1 += ks0 + 5u;
#undef TF_ROUND
    unsigned bits = x0 ^ x1;       // partitionable 32-bit combine
    unsigned fb = (bits >> 9) | 0x3f800000u;
    float f = __uint_as_float(fb) - 1.0f;
    const float tinyf = 1.1754943508222875e-38f;
    float u32v = fmaxf(tinyf, f * (1.0f - tinyf) + tinyf);
    out[i] = -log(-log((double)u32v));
}

// ---------------------------------------------------------------- pred1 + sampling (f64)
__global__ __launch_bounds__(64) void k_pred1(const double* __restrict__ E64, const float* __restrict__ fw,
    const float* __restrict__ fb, const double* __restrict__ gum, const int* __restrict__ tgt,
    const float* __restrict__ corr, float* __restrict__ pred1, float* __restrict__ ind,
    float* __restrict__ cmask)
{
    int g = blockIdx.x;
    int l = threadIdx.x;
    double acc[10];
#pragma unroll
    for (int c = 0; c < 10; ++c) acc[c] = 0.0;
    for (int i = l; i < 1280; i += 64) {
        double e = E64[(size_t)g * 1280 + i];
#pragma unroll
        for (int c = 0; c < 10; ++c) acc[c] = fma(e, (double)fw[i * 10 + c], acc[c]);
    }
#pragma unroll
    for (int c = 0; c < 10; ++c) {
        double v = acc[c];
        for (int o = 32; o > 0; o >>= 1) v += __shfl_down(v, o, 64);
        acc[c] = v;
    }
    if (l == 0) {
        double best = -1e300; int bi = 0;
        for (int c = 0; c < 10; ++c) {
            double p = acc[c] + (double)fb[c];
            pred1[g * 10 + c] = (float)p;
            double y = p + gum[g * 10 + c];
            if (y > best) { best = y; bi = c; }
        }
        ind[g] = (bi == tgt[g]) ? 1.f : 0.f;
        for (int f = 0; f < 16; ++f) cmask[g * 16 + f] = corr[bi * 16 + f];
    }
}

// ---------------------------------------------------------------- Q + feature_mask (f32)
__global__ __launch_bounds__(128) void k_q(const float* __restrict__ Eo, const float* __restrict__ w1,
    const float* __restrict__ b1, const float* __restrict__ w2, const float* __restrict__ b2,
    const float* __restrict__ cmask, float* __restrict__ Q, float* __restrict__ fm)
{
    int gk = blockIdx.x;
    int g = gk / 10;
    int h = threadIdx.x;
    __shared__ float e[128];
    __shared__ float hh[128];
    __shared__ float qv[16];
    __shared__ float pr[16];
    e[h] = Eo[(size_t)gk * D + h];
    __syncthreads();
    float acc = b1[h];
#pragma unroll 8
    for (int d = 0; d < D; ++d) acc = fmaf(e[d], w1[d * D + h], acc);
    hh[h] = fmaxf(acc, 0.f);
    __syncthreads();
    if (h < 16) {
        float s = b2[h];
        for (int d = 0; d < D; ++d) s = fmaf(hh[d], w2[d * 16 + h], s);
        qv[h] = s;
    }
    __syncthreads();
    if (h < 16) {
        float m = qv[0];
        for (int f = 1; f < 16; ++f) m = fmaxf(m, qv[f]);
        pr[h] = expf(qv[h] - m);
    }
    __syncthreads();
    if (h < 16) {
        float s = 0.f;
        for (int f = 0; f < 16; ++f) s += pr[f];
        float q = pr[h] / s;
        Q[(size_t)gk * 16 + h] = q;
        qv[h] = q * cmask[g * 16 + h];
    }
    __syncthreads();
    if (h == 0) {
        float s = 0.f;
        for (int f = 0; f < 16; ++f) s += qv[f];
        fm[gk] = s;
    }
}

// ---------------------------------------------------------------- pred2 (f64 accum from E64)
__global__ __launch_bounds__(64) void k_pred2(const double* __restrict__ E64, const float* __restrict__ fw,
    const float* __restrict__ fb, const float* __restrict__ fm, float* __restrict__ pred2)
{
    int g = blockIdx.x;
    int l = threadIdx.x;
    double acc[10];
#pragma unroll
    for (int c = 0; c < 10; ++c) acc[c] = 0.0;
    for (int i = l; i < 1280; i += 64) {
        int k = i >> 7;
        double e = E64[(size_t)g * 1280 + i] * (double)fm[g * 10 + k];
#pragma unroll
        for (int c = 0; c < 10; ++c) acc[c] = fma(e, (double)fw[i * 10 + c], acc[c]);
    }
#pragma unroll
    for (int c = 0; c < 10; ++c) {
        double v = acc[c];
        for (int o = 32; o > 0; o >>= 1) v += __shfl_down(v, o, 64);
        acc[c] = v;
    }
    if (l == 0)
        for (int c = 0; c < 10; ++c) pred2[g * 10 + c] = (float)(acc[c] + (double)fb[c]);
}

// ================================================================ host
extern "C" void kernel_launch(void* const* d_in, const int* in_sizes, int n_in,
                              void* d_out, int out_size, void* d_ws, size_t ws_size,
                              hipStream_t stream)
{
    const float* features = (const float*)d_in[0];
    const int*   W_row    = (const int*)d_in[1];
    const int*   W_col    = (const int*)d_in[2];
    const float* W_vals   = (const float*)d_in[3];
    const int*   gi       = (const int*)d_in[4];
    const int*   targets  = (const int*)d_in[5];
    const float* enc_w1   = (const float*)d_in[6];
    const float* enc_b1   = (const float*)d_in[7];
    const float* enc_w2   = (const float*)d_in[8];
    const float* enc_b2   = (const float*)d_in[9];
    const float* bn_gamma = (const float*)d_in[10];
    const float* bn_beta  = (const float*)d_in[11];
    const float* concat_w1= (const float*)d_in[12];
    const float* concat_b1= (const float*)d_in[13];
    const float* concat_w2= (const float*)d_in[14];
    const float* concat_b2= (const float*)d_in[15];
    const float* smlp_w1  = (const float*)d_in[16];
    const float* smlp_b1  = (const float*)d_in[17];
    const float* smlp_w2  = (const float*)d_in[18];
    const float* smlp_b2  = (const float*)d_in[19];
    const float* proto_w1 = (const float*)d_in[20];
    const float* proto_b1 = (const float*)d_in[21];
    const float* proto_w2 = (const float*)d_in[22];
    const float* proto_b2 = (const float*)d_in[23];
    const float* final_w  = (const float*)d_in[24];
    const float* final_b  = (const float*)d_in[25];
    const float* corr_i   = (const float*)d_in[26];
    const float* corr_a   = (const float*)d_in[27];

    float* out = (float*)d_out;
    float* o_pred1 = out + 0;
    float* o_pred2 = out + 5120;
    float* o_S     = out + 10240;
    float* o_H     = out + 665600;
    float* o_ind   = out + 9054208;
    float* o_E     = out + 9054720;
    float* o_Q     = out + 9710080;

    // ---------------- workspace arena
    char* base = (char*)d_ws;
    size_t off = 0;
    auto alloc = [&](size_t n) -> char* {
        char* r = base + off;
        off = (off + n + 255) & ~(size_t)255;
        return r;
    };
    int*    d_off   = (int*)alloc(513 * 4);
    double* d_a     = (double*)alloc(256 * 8);
    double* d_c     = (double*)alloc(256 * 8);
    double* d_gum   = (double*)alloc(5120 * 8);
    float*  d_corr  = (float*)alloc(160 * 4);
    float*  d_cmask = (float*)alloc(512 * 16 * 4);
    float*  d_fm    = (float*)alloc(5120 * 4);
    double* psum    = (double*)alloc(2 * 512 * 128 * 8);
    double* pssq    = (double*)alloc(2 * 512 * 128 * 8);
    int*    cnt     = (int*)alloc((size_t)NN * 4);
    int*    excl    = (int*)alloc((size_t)NN * 4);
    int*    bsum    = (int*)alloc(256 * 4);
    int*    boff    = (int*)alloc(256 * 4);
    int*    rowptr  = (int*)alloc((size_t)(NN + 1) * 4);
    int*    cursor  = (int*)alloc((size_t)NN * 4);
    int*    ecol    = (int*)alloc((size_t)EE * 4);
    float*  evalv   = (float*)alloc((size_t)EE * 4);
    double* E64     = (double*)alloc((size_t)GG * 1280 * 8);   // 5.24 MB

    const size_t SZ = (size_t)NN * D * 4;   // 32 MiB per f32 tensor
    float* rot0 = (float*)alloc(SZ);
    float* rot1 = (float*)alloc(SZ);
    float* rot2 = (float*)alloc(SZ);
    float* h0   = (float*)alloc(SZ);
    float* h1   = (float*)alloc(SZ);
    float* h2   = (float*)alloc(SZ);
    float* h3   = (float*)alloc(SZ);
    float* Tenc = h0;        // N x 256 f32 spans h0+h1; both dead until mean2/k_hidden write them
    float* hid2 = rot0;      // smlp hidden reuses rot region after prop loop

    // ---------------- small precomputations
    k_off   <<<3, 256, 0, stream>>>(gi, d_off);
    k_corr  <<<1, 256, 0, stream>>>(corr_i, corr_a, d_corr);
    k_gumbel<<<20, 256, 0, stream>>>(d_gum);

    // ---------------- CSR build
    hipMemsetAsync(cnt, 0, (size_t)NN * 4, stream);
    k_hist   <<<EE / 256, 256, 0, stream>>>(W_row, cnt);
    k_scan1  <<<256, 256, 0, stream>>>(cnt, excl, bsum);
    k_scan2  <<<1, 256, 0, stream>>>(bsum, boff);
    k_scan3  <<<256, 256, 0, stream>>>(excl, boff, rowptr, cursor);
    k_scatter<<<EE / 256, 256, 0, stream>>>(W_row, W_col, W_vals, cursor, ecol, evalv);

    // ---------------- encoder (f32)
    k_gemm<<<dim3(2, 512), 256, 0, stream>>>(features, enc_w1,             enc_b1,       Tenc, NN, 256, 128, 1);
    k_gemm<<<dim3(1, 512), 256, 0, stream>>>(Tenc,     enc_w2,             enc_b2,       rot0, NN, 128, 256, 0);
    k_gemm<<<dim3(2, 512), 256, 0, stream>>>(features, enc_w1 + 128 * 256, enc_b1 + 256, Tenc, NN, 256, 128, 1);
    k_gemm<<<dim3(1, 512), 256, 0, stream>>>(Tenc,     enc_w2 + 256 * 128, enc_b2 + 128, rot1, NN, 128, 256, 0);
    k_mean2<<<8192, 256, 0, stream>>>((const f4*)rot0, (const f4*)rot1, (f4*)h0);

    // ---------------- propagation loop (two SEQUENTIAL spmm dispatches — no aliasing race)
    float* cur0 = rot0;
    float* cur1 = rot1;
    float* fre  = rot2;
    float* hbuf[4] = { h0, h1, h2, h3 };
    for (int p = 0; p < 3; ++p) {
        k_spmm<<<NN / 4, 256, 0, stream>>>(rowptr, ecol, evalv, cur0, fre);
        k_spmm<<<NN / 4, 256, 0, stream>>>(rowptr, ecol, evalv, cur1, cur0);
        k_bnstats2<<<dim3(512, 2), 128, 0, stream>>>(fre, cur0, psum, pssq);
        k_bnfin<<<1, 256, 0, stream>>>(psum, pssq, bn_gamma, bn_beta, d_a, d_c, 2, p);
        k_hidden<<<8192, 256, 0, stream>>>((const f4*)fre, (const f4*)cur0, d_a, d_c, (f4*)hbuf[1 + p]);
        float* t0 = fre; float* t1 = cur0; float* t2 = cur1;
        cur0 = t0; cur1 = t1; fre = t2;
    }

    // ---------------- concat MLP -> o_H, BN+relu in place
    k_concat<<<8192, 256, 0, stream>>>((const f4*)h0, (const f4*)h1, (const f4*)h2, (const f4*)h3,
                                       concat_w1, concat_b1, concat_w2, concat_b2, (f4*)o_H);
    k_bnstats2<<<dim3(512, 1), 128, 0, stream>>>(o_H, o_H, psum, pssq);
    k_bnfin<<<1, 256, 0, stream>>>(psum, pssq, bn_gamma, bn_beta, d_a, d_c, 1, 3);
    k_bnapply<<<8192, 256, 0, stream>>>((f4*)o_H, d_a, d_c);

    // ---------------- S_all
    k_gemm<<<dim3(1, 512), 256, 0, stream>>>(o_H, smlp_w1, smlp_b1, hid2, NN, 128, 128, 1);
    k_s<<<256, 256, 0, stream>>>(hid2, smlp_w2, smlp_b2, o_S);

    // ---------------- E_all, heads
    k_eall <<<512, 256, 0, stream>>>(o_S, o_H, d_off, o_E, E64);
    k_pred1<<<512, 64, 0, stream>>>(E64, final_w, final_b, d_gum, targets, d_corr,
                                    o_pred1, o_ind, d_cmask);
    k_q    <<<5120, 128, 0, stream>>>(o_E, proto_w1, proto_b1, proto_w2, proto_b2,
                                      d_cmask, o_Q, d_fm);
    k_pred2<<<512, 64, 0, stream>>>(E64, final_w, final_b, d_fm, o_pred2);

    (void)in_sizes; (void)n_in; (void)out_size; (void)ws_size;
}

// Round 9
// 1325.059 us; speedup vs baseline: 1.5489x; 1.0130x over previous
//
#include <hip/hip_runtime.h>
#include <math.h>

#define NN 65536
#define EE 1048576
#define GG 512
#define D  128

typedef float4 f4;

// ---------------------------------------------------------------- GEMM (fp32, 128x128 tile, 8x8 micro, split 4+4 layout)
// C[M,N] = act(A[M,K] @ B[K,N] + bias[N]); M%128==0, N%128==0, K%16==0
// Thread (tx,ty) owns rows {ty*4+i, 64+ty*4+i} x cols {tx*4+j, 64+tx*4+j}:
// stride-4 b128 LDS reads (2-way aliasing = free) instead of stride-8 (4-way conflict).
__global__ __launch_bounds__(256) void k_gemm(const float* __restrict__ A,
    const float* __restrict__ B, const float* __restrict__ bias,
    float* __restrict__ C, int M, int N, int K, int relu)
{
    __shared__ __align__(16) float As[16][132];
    __shared__ __align__(16) float Bs[16][132];
    int tid = threadIdx.x;
    int tx = tid & 15, ty = tid >> 4;
    int row0 = blockIdx.y * 128, col0 = blockIdx.x * 128;
    float acc[8][8];
#pragma unroll
    for (int i = 0; i < 8; ++i)
#pragma unroll
        for (int j = 0; j < 8; ++j) acc[i][j] = 0.f;
    int ar = tid >> 1, ac = (tid & 1) * 8;
    int br = tid >> 4, bc = (tid & 15) * 8;
    const float* aptr = A + (size_t)(row0 + ar) * K + ac;
    const float* bptr = B + (size_t)br * N + col0 + bc;

    // preload tile 0
    f4 pa0 = *(const f4*)(aptr);
    f4 pa1 = *(const f4*)(aptr + 4);
    f4 pb0 = *(const f4*)(bptr);
    f4 pb1 = *(const f4*)(bptr + 4);

    for (int k0 = 0; k0 < K; k0 += 16) {
        As[ac + 0][ar] = pa0.x; As[ac + 1][ar] = pa0.y; As[ac + 2][ar] = pa0.z; As[ac + 3][ar] = pa0.w;
        As[ac + 4][ar] = pa1.x; As[ac + 5][ar] = pa1.y; As[ac + 6][ar] = pa1.z; As[ac + 7][ar] = pa1.w;
        *(f4*)&Bs[br][bc] = pb0; *(f4*)&Bs[br][bc + 4] = pb1;
        __syncthreads();
        if (k0 + 16 < K) {
            pa0 = *(const f4*)(aptr + k0 + 16);
            pa1 = *(const f4*)(aptr + k0 + 16 + 4);
            pb0 = *(const f4*)(bptr + (size_t)(k0 + 16) * N);
            pb1 = *(const f4*)(bptr + (size_t)(k0 + 16) * N + 4);
        }
#pragma unroll
        for (int kk = 0; kk < 16; ++kk) {
            float a[8], b[8];
            *(f4*)&a[0] = *(const f4*)&As[kk][ty * 4];
            *(f4*)&a[4] = *(const f4*)&As[kk][64 + ty * 4];
            *(f4*)&b[0] = *(const f4*)&Bs[kk][tx * 4];
            *(f4*)&b[4] = *(const f4*)&Bs[kk][64 + tx * 4];
#pragma unroll
            for (int i = 0; i < 8; ++i)
#pragma unroll
                for (int j = 0; j < 8; ++j) acc[i][j] = fmaf(a[i], b[j], acc[i][j]);
        }
        __syncthreads();
    }
    f4 bia0 = *(const f4*)(bias + col0 + tx * 4);
    f4 bia1 = *(const f4*)(bias + col0 + 64 + tx * 4);
#pragma unroll
    for (int i = 0; i < 8; ++i) {
        int r = row0 + ((i < 4) ? (ty * 4 + i) : (64 + ty * 4 + i - 4));
        f4 v0, v1;
#pragma unroll
        for (int j = 0; j < 4; ++j) {
            float u0 = acc[i][j] + (&bia0.x)[j];
            float u1 = acc[i][j + 4] + (&bia1.x)[j];
            if (relu) { u0 = fmaxf(u0, 0.f); u1 = fmaxf(u1, 0.f); }
            (&v0.x)[j] = u0; (&v1.x)[j] = u1;
        }
        *(f4*)(C + (size_t)r * N + col0 + tx * 4) = v0;
        *(f4*)(C + (size_t)r * N + col0 + 64 + tx * 4) = v1;
    }
}

// ---------------------------------------------------------------- CSR build
__global__ __launch_bounds__(256) void k_hist(const int* __restrict__ Wr, int* __restrict__ cnt)
{
    int e = blockIdx.x * 256 + threadIdx.x;
    if (e < EE) atomicAdd(&cnt[Wr[e]], 1);
}

__global__ __launch_bounds__(256) void k_scan1(const int* __restrict__ cnt,
    int* __restrict__ excl, int* __restrict__ bsum)
{
    __shared__ int s[256];
    int b = blockIdx.x, t = threadIdx.x;
    int v = cnt[b * 256 + t];
    s[t] = v; __syncthreads();
    for (int o = 1; o < 256; o <<= 1) {
        int x = (t >= o) ? s[t - o] : 0;
        __syncthreads();
        s[t] += x;
        __syncthreads();
    }
    excl[b * 256 + t] = s[t] - v;
    if (t == 255) bsum[b] = s[255];
}

__global__ void k_scan2(const int* __restrict__ bsum, int* __restrict__ boff)
{
    __shared__ int s[256];
    int t = threadIdx.x;
    int v = bsum[t]; s[t] = v; __syncthreads();
    for (int o = 1; o < 256; o <<= 1) {
        int x = (t >= o) ? s[t - o] : 0;
        __syncthreads();
        s[t] += x;
        __syncthreads();
    }
    boff[t] = s[t] - v;
}

__global__ __launch_bounds__(256) void k_scan3(const int* __restrict__ excl, const int* __restrict__ boff,
    int* __restrict__ rowptr, int* __restrict__ cursor)
{
    int i = blockIdx.x * 256 + threadIdx.x;
    int v = excl[i] + boff[i >> 8];
    rowptr[i] = v; cursor[i] = v;
    if (i == 0) rowptr[NN] = EE;
}

__global__ __launch_bounds__(256) void k_scatter(const int* __restrict__ Wr, const int* __restrict__ Wc,
    const float* __restrict__ Wv, int* __restrict__ cursor, int* __restrict__ ecol, float* __restrict__ ev)
{
    int e = blockIdx.x * 256 + threadIdx.x;
    if (e >= EE) return;
    int r = Wr[e];
    int p = atomicAdd(&cursor[r], 1);
    ecol[p] = Wc[e]; ev[p] = Wv[e];
}

// ---------------------------------------------------------------- SpMM (CSR, wave/row, 4-edge chunks)
// Two SEQUENTIAL dispatches per step (round-6 fusion raced; round-8 4th buffer overflowed ws).
__global__ __launch_bounds__(256) void k_spmm(const int* __restrict__ rowptr,
    const int* __restrict__ ecol, const float* __restrict__ eval,
    const float* __restrict__ X, float* __restrict__ Y)
{
    int row = blockIdx.x * 4 + (threadIdx.x >> 6);
    int lane = threadIdx.x & 63;
    int s = rowptr[row], e = rowptr[row + 1];
    float a0 = 0.f, a1 = 0.f;
    int i = s;
    for (; i + 4 <= e; i += 4) {
        int   c0 = ecol[i], c1 = ecol[i + 1], c2 = ecol[i + 2], c3 = ecol[i + 3];
        float w0 = eval[i], w1 = eval[i + 1], w2 = eval[i + 2], w3 = eval[i + 3];
        float2 x0 = *(const float2*)(X + (size_t)c0 * D + lane * 2);
        float2 x1 = *(const float2*)(X + (size_t)c1 * D + lane * 2);
        float2 x2 = *(const float2*)(X + (size_t)c2 * D + lane * 2);
        float2 x3 = *(const float2*)(X + (size_t)c3 * D + lane * 2);
        a0 = fmaf(w0, x0.x, a0); a1 = fmaf(w0, x0.y, a1);
        a0 = fmaf(w1, x1.x, a0); a1 = fmaf(w1, x1.y, a1);
        a0 = fmaf(w2, x2.x, a0); a1 = fmaf(w2, x2.y, a1);
        a0 = fmaf(w3, x3.x, a0); a1 = fmaf(w3, x3.y, a1);
    }
    for (; i < e; ++i) {
        int cc = ecol[i];
        float w = eval[i];
        float2 x = *(const float2*)(X + (size_t)cc * D + lane * 2);
        a0 = fmaf(w, x.x, a0);
        a1 = fmaf(w, x.y, a1);
    }
    *(float2*)(Y + (size_t)row * D + lane * 2) = make_float2(a0, a1);
}

// ---------------------------------------------------------------- BN stats (dual matrix read-only fuse, f64 partials)
__global__ __launch_bounds__(128) void k_bnstats2(const float* __restrict__ X0, const float* __restrict__ X1,
    double* __restrict__ psum, double* __restrict__ pssq)
{
    const float* __restrict__ X = blockIdx.y ? X1 : X0;
    int d = threadIdx.x;
    int r0 = blockIdx.x * 128;
    double s = 0.0, q = 0.0;
#pragma unroll 4
    for (int r = r0; r < r0 + 128; ++r) {
        double v = (double)X[(size_t)r * D + d];
        s += v; q = fma(v, v, q);
    }
    psum[blockIdx.y * 65536 + blockIdx.x * 128 + d] = s;
    pssq[blockIdx.y * 65536 + blockIdx.x * 128 + d] = q;
}

__global__ void k_bnfin(const double* __restrict__ psum, const double* __restrict__ pssq,
    const float* __restrict__ gamma, const float* __restrict__ beta,
    double* __restrict__ a, double* __restrict__ c, int nb, int layer)
{
    int t = threadIdx.x;
    if (t >= nb * 128) return;
    int blk = t >> 7, d = t & 127;
    const double* ps = psum + blk * 65536;
    const double* pq = pssq + blk * 65536;
    double s = 0.0, q = 0.0;
    for (int j = 0; j < 512; ++j) { s += ps[j * 128 + d]; q += pq[j * 128 + d]; }
    double m = s * (1.0 / 65536.0);
    double v = q * (1.0 / 65536.0) - m * m;
    double aa = (double)gamma[layer * 128 + d] / sqrt(v + 1e-5);
    a[t] = aa;
    c[t] = (double)beta[layer * 128 + d] - m * aa;
}

// ---------------------------------------------------------------- elementwise (f32, f4)
__global__ __launch_bounds__(256) void k_mean2(const f4* __restrict__ x0, const f4* __restrict__ x1,
                                               f4* __restrict__ o)
{
    int i = blockIdx.x * 256 + threadIdx.x;
    f4 a = x0[i], b = x1[i];
    f4 r;
    r.x = 0.5f * (a.x + b.x); r.y = 0.5f * (a.y + b.y);
    r.z = 0.5f * (a.z + b.z); r.w = 0.5f * (a.w + b.w);
    o[i] = r;
}

__global__ __launch_bounds__(256) void k_hidden(const f4* __restrict__ p0, const f4* __restrict__ p1,
    const double* __restrict__ a, const double* __restrict__ c, f4* __restrict__ o)
{
    int i = blockIdx.x * 256 + threadIdx.x;
    int d4 = (i & 31) * 4;
    f4 x = p0[i], y = p1[i];
    f4 r;
#pragma unroll
    for (int j = 0; j < 4; ++j) {
        float a0 = (float)a[d4 + j], c0 = (float)c[d4 + j];
        float a1 = (float)a[128 + d4 + j], c1 = (float)c[128 + d4 + j];
        float xv = (&x.x)[j], yv = (&y.x)[j];
        (&r.x)[j] = 0.5f * (fmaxf(fmaf(xv, a0, c0), 0.f) + fmaxf(fmaf(yv, a1, c1), 0.f));
    }
    o[i] = r;
}

__global__ __launch_bounds__(256) void k_bnapply(f4* __restrict__ H,
    const double* __restrict__ a, const double* __restrict__ c)
{
    int i = blockIdx.x * 256 + threadIdx.x;
    int d4 = (i & 31) * 4;
    f4 x = H[i];
#pragma unroll
    for (int j = 0; j < 4; ++j) {
        float a0 = (float)a[d4 + j], c0 = (float)c[d4 + j];
        (&x.x)[j] = fmaxf(fmaf((&x.x)[j], a0, c0), 0.f);
    }
    H[i] = x;
}

// ---------------------------------------------------------------- concat MLP (f32, 4 elems/thread, f4 weight reads)
__global__ __launch_bounds__(256) void k_concat(const f4* __restrict__ h0, const f4* __restrict__ h1,
    const f4* __restrict__ h2, const f4* __restrict__ h3,
    const float* __restrict__ w1, const float* __restrict__ b1,
    const float* __restrict__ w2, const float* __restrict__ b2,
    f4* __restrict__ Hpre)
{
    __shared__ __align__(16) float sw0[128], sw1_[128], sw2_[128], sw3[128], sv[128], sb[128];
    int t = threadIdx.x;
    if (t < 128) {
        sw0[t] = w1[t];        sw1_[t] = w1[128 + t];
        sw2_[t] = w1[256 + t]; sw3[t]  = w1[384 + t];
        sv[t]  = w2[t];        sb[t]   = b1[t];
    }
    __syncthreads();
    int i = blockIdx.x * 256 + t;  // f4 units, < N*D/4
    f4 x0 = h0[i], x1 = h1[i], x2 = h2[i], x3 = h3[i];
    float bb2 = b2[0];
    float acc0 = bb2, acc1 = bb2, acc2 = bb2, acc3 = bb2;
    for (int h4 = 0; h4 < D; h4 += 4) {
        f4 cw0 = *(const f4*)&sw0[h4];
        f4 cw1 = *(const f4*)&sw1_[h4];
        f4 cw2 = *(const f4*)&sw2_[h4];
        f4 cw3 = *(const f4*)&sw3[h4];
        f4 cbb = *(const f4*)&sb[h4];
        f4 cvv = *(const f4*)&sv[h4];
#pragma unroll
        for (int j = 0; j < 4; ++j) {
            float w0 = (&cw0.x)[j], ww1 = (&cw1.x)[j], ww2 = (&cw2.x)[j], w3 = (&cw3.x)[j];
            float bb = (&cbb.x)[j], vv = (&cvv.x)[j];
            float t0 = fmaf(x3.x, w3, fmaf(x2.x, ww2, fmaf(x1.x, ww1, fmaf(x0.x, w0, bb))));
            float t1 = fmaf(x3.y, w3, fmaf(x2.y, ww2, fmaf(x1.y, ww1, fmaf(x0.y, w0, bb))));
            float t2 = fmaf(x3.z, w3, fmaf(x2.z, ww2, fmaf(x1.z, ww1, fmaf(x0.z, w0, bb))));
            float t3 = fmaf(x3.w, w3, fmaf(x2.w, ww2, fmaf(x1.w, ww1, fmaf(x0.w, w0, bb))));
            acc0 = fmaf(fmaxf(t0, 0.f), vv, acc0);
            acc1 = fmaf(fmaxf(t1, 0.f), vv, acc1);
            acc2 = fmaf(fmaxf(t2, 0.f), vv, acc2);
            acc3 = fmaf(fmaxf(t3, 0.f), vv, acc3);
        }
    }
    f4 r; r.x = acc0; r.y = acc1; r.z = acc2; r.w = acc3;
    Hpre[i] = r;
}

// ---------------------------------------------------------------- S = softmax(hid @ w2 + b2) (f32)
__global__ __launch_bounds__(256) void k_s(const float* __restrict__ hid,
    const float* __restrict__ w2, const float* __restrict__ b2, float* __restrict__ S)
{
    int n = blockIdx.x * 256 + threadIdx.x;
    if (n >= NN) return;
    const float* hr = hid + (size_t)n * D;
    float s[10];
#pragma unroll
    for (int k = 0; k < 10; ++k) s[k] = b2[k];
    for (int h = 0; h < D; h += 4) {
        f4 hv = *(const f4*)(hr + h);
#pragma unroll
        for (int k = 0; k < 10; ++k) {
            s[k] = fmaf(hv.x, w2[(h + 0) * 10 + k], s[k]);
            s[k] = fmaf(hv.y, w2[(h + 1) * 10 + k], s[k]);
            s[k] = fmaf(hv.z, w2[(h + 2) * 10 + k], s[k]);
            s[k] = fmaf(hv.w, w2[(h + 3) * 10 + k], s[k]);
        }
    }
    float m = s[0];
#pragma unroll
    for (int k = 1; k < 10; ++k) m = fmaxf(m, s[k]);
    float e[10], sum = 0.f;
#pragma unroll
    for (int k = 0; k < 10; ++k) { e[k] = expf(s[k] - m); sum += e[k]; }
    float inv = 1.f / sum;
#pragma unroll
    for (int k = 0; k < 10; ++k) S[(size_t)n * 10 + k] = e[k] * inv;
}

// ---------------------------------------------------------------- E_all (f32 in, f64 accum, dual store)
__global__ __launch_bounds__(256) void k_eall(const float* __restrict__ S, const float* __restrict__ H,
    const int* __restrict__ off, float* __restrict__ Eo, double* __restrict__ E64)
{
    int g = blockIdx.x;
    int d = threadIdx.x & 127;
    int half = threadIdx.x >> 7;
    double acc[5] = {0.0, 0.0, 0.0, 0.0, 0.0};
    int s0 = off[g], s1 = off[g + 1];
    for (int n = s0; n < s1; ++n) {
        double hv = (double)H[(size_t)n * D + d];
#pragma unroll
        for (int j = 0; j < 5; ++j) acc[j] = fma((double)S[(size_t)n * 10 + half * 5 + j], hv, acc[j]);
    }
#pragma unroll
    for (int j = 0; j < 5; ++j) {
        size_t o = (size_t)g * 1280 + (half * 5 + j) * D + d;
        Eo[o] = (float)acc[j];
        E64[o] = acc[j];
    }
}

// ---------------------------------------------------------------- graph offsets
__global__ void k_off(const int* __restrict__ gi, int* __restrict__ off)
{
    int g = blockIdx.x * 256 + threadIdx.x;
    if (g > GG) return;
    int lo = 0, hi = NN;
    while (lo < hi) { int mid = (lo + hi) >> 1; if (gi[mid] < g) lo = mid + 1; else hi = mid; }
    off[g] = lo;
}

// ---------------------------------------------------------------- corr
__global__ void k_corr(const float* __restrict__ ci, const float* __restrict__ ca, float* __restrict__ corr)
{
    int t = threadIdx.x;
    if (t >= 160) return;
    int r = t / 16, c = t % 16;
    double m = -1e300;
    for (int i = 0; i < 10; ++i) m = fmax(m, (double)ci[i * 16 + c]);
    double s = 0.0;
    for (int i = 0; i < 10; ++i) s += exp((double)ci[i * 16 + c] - m);
    double vi = exp((double)ci[r * 16 + c] - m) / s;
    double m2 = -1e300;
    for (int j = 0; j < 16; ++j) m2 = fmax(m2, (double)ca[r * 16 + j]);
    double s2 = 0.0;
    for (int j = 0; j < 16; ++j) s2 += exp((double)ca[r * 16 + j] - m2);
    double va = exp((double)ca[r * 16 + c] - m2) / s2;
    corr[t] = (float)(vi * va);
}

// ---------------------------------------------------------------- JAX threefry gumbel — PARTITIONABLE (verified)
__device__ __forceinline__ unsigned tf_rotl(unsigned x, unsigned n) { return (x << n) | (x >> (32u - n)); }

__global__ void k_gumbel(double* __restrict__ out)
{
    int i = blockIdx.x * 256 + threadIdx.x;
    if (i >= 5120) return;
    unsigned x0 = 0u;              // hi32 of 64-bit counter
    unsigned x1 = (unsigned)i;     // lo32
    const unsigned ks0 = 0u, ks1 = 42u;
    const unsigned ks2 = 0x1BD11BDAu ^ ks0 ^ ks1;
    x0 += ks0; x1 += ks1;
#define TF_ROUND(rr) { x0 += x1; x1 = tf_rotl(x1, rr); x1 ^= x0; }
    TF_ROUND(13) TF_ROUND(15) TF_ROUND(26) TF_ROUND(6)
    x0 += ks1; x1 += ks2 + 1u;
    TF_ROUND(17) TF_ROUND(29) TF_ROUND(16) TF_ROUND(24)
    x0 += ks2; x1 += ks0 + 2u;
    TF_ROUND(13) TF_ROUND(15) TF_ROUND(26) TF_ROUND(6)
    x0 += ks0; x1 += ks1 + 3u;
    TF_ROUND(17) TF_ROUND(29) TF_ROUND(16) TF_ROUND(24)
    x0 += ks1; x1 += ks2 + 4u;
    TF_ROUND(13) TF_ROUND(15) TF_ROUND(26) TF_ROUND(6)
    x0 += ks2; x1 += ks0 + 5u;
#undef TF_ROUND
    unsigned bits = x0 ^ x1;       // partitionable 32-bit combine
    unsigned fb = (bits >> 9) | 0x3f800000u;
    float f = __uint_as_float(fb) - 1.0f;
    const float tinyf = 1.1754943508222875e-38f;
    float u32v = fmaxf(tinyf, f * (1.0f - tinyf) + tinyf);
    out[i] = -log(-log((double)u32v));
}

// ---------------------------------------------------------------- pred1 + sampling (f64)
__global__ __launch_bounds__(64) void k_pred1(const double* __restrict__ E64, const float* __restrict__ fw,
    const float* __restrict__ fb, const double* __restrict__ gum, const int* __restrict__ tgt,
    const float* __restrict__ corr, float* __restrict__ pred1, float* __restrict__ ind,
    float* __restrict__ cmask)
{
    int g = blockIdx.x;
    int l = threadIdx.x;
    double acc[10];
#pragma unroll
    for (int c = 0; c < 10; ++c) acc[c] = 0.0;
    for (int i = l; i < 1280; i += 64) {
        double e = E64[(size_t)g * 1280 + i];
#pragma unroll
        for (int c = 0; c < 10; ++c) acc[c] = fma(e, (double)fw[i * 10 + c], acc[c]);
    }
#pragma unroll
    for (int c = 0; c < 10; ++c) {
        double v = acc[c];
        for (int o = 32; o > 0; o >>= 1) v += __shfl_down(v, o, 64);
        acc[c] = v;
    }
    if (l == 0) {
        double best = -1e300; int bi = 0;
        for (int c = 0; c < 10; ++c) {
            double p = acc[c] + (double)fb[c];
            pred1[g * 10 + c] = (float)p;
            double y = p + gum[g * 10 + c];
            if (y > best) { best = y; bi = c; }
        }
        ind[g] = (bi == tgt[g]) ? 1.f : 0.f;
        for (int f = 0; f < 16; ++f) cmask[g * 16 + f] = corr[bi * 16 + f];
    }
}

// ---------------------------------------------------------------- Q + feature_mask (f32)
__global__ __launch_bounds__(128) void k_q(const float* __restrict__ Eo, const float* __restrict__ w1,
    const float* __restrict__ b1, const float* __restrict__ w2, const float* __restrict__ b2,
    const float* __restrict__ cmask, float* __restrict__ Q, float* __restrict__ fm)
{
    int gk = blockIdx.x;
    int g = gk / 10;
    int h = threadIdx.x;
    __shared__ float e[128];
    __shared__ float hh[128];
    __shared__ float qv[16];
    __shared__ float pr[16];
    e[h] = Eo[(size_t)gk * D + h];
    __syncthreads();
    float acc = b1[h];
#pragma unroll 8
    for (int d = 0; d < D; ++d) acc = fmaf(e[d], w1[d * D + h], acc);
    hh[h] = fmaxf(acc, 0.f);
    __syncthreads();
    if (h < 16) {
        float s = b2[h];
        for (int d = 0; d < D; ++d) s = fmaf(hh[d], w2[d * 16 + h], s);
        qv[h] = s;
    }
    __syncthreads();
    if (h < 16) {
        float m = qv[0];
        for (int f = 1; f < 16; ++f) m = fmaxf(m, qv[f]);
        pr[h] = expf(qv[h] - m);
    }
    __syncthreads();
    if (h < 16) {
        float s = 0.f;
        for (int f = 0; f < 16; ++f) s += pr[f];
        float q = pr[h] / s;
        Q[(size_t)gk * 16 + h] = q;
        qv[h] = q * cmask[g * 16 + h];
    }
    __syncthreads();
    if (h == 0) {
        float s = 0.f;
        for (int f = 0; f < 16; ++f) s += qv[f];
        fm[gk] = s;
    }
}

// ---------------------------------------------------------------- pred2 (f64 accum from E64)
__global__ __launch_bounds__(64) void k_pred2(const double* __restrict__ E64, const float* __restrict__ fw,
    const float* __restrict__ fb, const float* __restrict__ fm, float* __restrict__ pred2)
{
    int g = blockIdx.x;
    int l = threadIdx.x;
    double acc[10];
#pragma unroll
    for (int c = 0; c < 10; ++c) acc[c] = 0.0;
    for (int i = l; i < 1280; i += 64) {
        int k = i >> 7;
        double e = E64[(size_t)g * 1280 + i] * (double)fm[g * 10 + k];
#pragma unroll
        for (int c = 0; c < 10; ++c) acc[c] = fma(e, (double)fw[i * 10 + c], acc[c]);
    }
#pragma unroll
    for (int c = 0; c < 10; ++c) {
        double v = acc[c];
        for (int o = 32; o > 0; o >>= 1) v += __shfl_down(v, o, 64);
        acc[c] = v;
    }
    if (l == 0)
        for (int c = 0; c < 10; ++c) pred2[g * 10 + c] = (float)(acc[c] + (double)fb[c]);
}

// ================================================================ host
extern "C" void kernel_launch(void* const* d_in, const int* in_sizes, int n_in,
                              void* d_out, int out_size, void* d_ws, size_t ws_size,
                              hipStream_t stream)
{
    const float* features = (const float*)d_in[0];
    const int*   W_row    = (const int*)d_in[1];
    const int*   W_col    = (const int*)d_in[2];
    const float* W_vals   = (const float*)d_in[3];
    const int*   gi       = (const int*)d_in[4];
    const int*   targets  = (const int*)d_in[5];
    const float* enc_w1   = (const float*)d_in[6];
    const float* enc_b1   = (const float*)d_in[7];
    const float* enc_w2   = (const float*)d_in[8];
    const float* enc_b2   = (const float*)d_in[9];
    const float* bn_gamma = (const float*)d_in[10];
    const float* bn_beta  = (const float*)d_in[11];
    const float* concat_w1= (const float*)d_in[12];
    const float* concat_b1= (const float*)d_in[13];
    const float* concat_w2= (const float*)d_in[14];
    const float* concat_b2= (const float*)d_in[15];
    const float* smlp_w1  = (const float*)d_in[16];
    const float* smlp_b1  = (const float*)d_in[17];
    const float* smlp_w2  = (const float*)d_in[18];
    const float* smlp_b2  = (const float*)d_in[19];
    const float* proto_w1 = (const float*)d_in[20];
    const float* proto_b1 = (const float*)d_in[21];
    const float* proto_w2 = (const float*)d_in[22];
    const float* proto_b2 = (const float*)d_in[23];
    const float* final_w  = (const float*)d_in[24];
    const float* final_b  = (const float*)d_in[25];
    const float* corr_i   = (const float*)d_in[26];
    const float* corr_a   = (const float*)d_in[27];

    float* out = (float*)d_out;
    float* o_pred1 = out + 0;
    float* o_pred2 = out + 5120;
    float* o_S     = out + 10240;
    float* o_H     = out + 665600;
    float* o_ind   = out + 9054208;
    float* o_E     = out + 9054720;
    float* o_Q     = out + 9710080;

    // ---------------- workspace arena (total ~240 MiB — proven to fit in rounds 5/7)
    char* base = (char*)d_ws;
    size_t off = 0;
    auto alloc = [&](size_t n) -> char* {
        char* r = base + off;
        off = (off + n + 255) & ~(size_t)255;
        return r;
    };
    int*    d_off   = (int*)alloc(513 * 4);
    double* d_a     = (double*)alloc(256 * 8);
    double* d_c     = (double*)alloc(256 * 8);
    double* d_gum   = (double*)alloc(5120 * 8);
    float*  d_corr  = (float*)alloc(160 * 4);
    float*  d_cmask = (float*)alloc(512 * 16 * 4);
    float*  d_fm    = (float*)alloc(5120 * 4);
    double* psum    = (double*)alloc(2 * 512 * 128 * 8);
    double* pssq    = (double*)alloc(2 * 512 * 128 * 8);
    int*    cnt     = (int*)alloc((size_t)NN * 4);
    int*    excl    = (int*)alloc((size_t)NN * 4);
    int*    bsum    = (int*)alloc(256 * 4);
    int*    boff    = (int*)alloc(256 * 4);
    int*    rowptr  = (int*)alloc((size_t)(NN + 1) * 4);
    int*    cursor  = (int*)alloc((size_t)NN * 4);
    int*    ecol    = (int*)alloc((size_t)EE * 4);
    float*  evalv   = (float*)alloc((size_t)EE * 4);
    double* E64     = (double*)alloc((size_t)GG * 1280 * 8);   // 5.24 MB

    const size_t SZ = (size_t)NN * D * 4;   // 32 MiB per f32 tensor
    float* rot0 = (float*)alloc(SZ);
    float* rot1 = (float*)alloc(SZ);
    float* rot2 = (float*)alloc(SZ);
    float* h0   = (float*)alloc(SZ);
    float* h1   = (float*)alloc(SZ);
    float* h2   = (float*)alloc(SZ);
    float* h3   = (float*)alloc(SZ);
    float* Tenc = h0;        // N x 256 f32 spans h0+h1; both dead until mean2/k_hidden write them
    float* hid2 = rot0;      // smlp hidden reuses rot region after prop loop

    // ---------------- small precomputations
    k_off   <<<3, 256, 0, stream>>>(gi, d_off);
    k_corr  <<<1, 256, 0, stream>>>(corr_i, corr_a, d_corr);
    k_gumbel<<<20, 256, 0, stream>>>(d_gum);

    // ---------------- CSR build
    hipMemsetAsync(cnt, 0, (size_t)NN * 4, stream);
    k_hist   <<<EE / 256, 256, 0, stream>>>(W_row, cnt);
    k_scan1  <<<256, 256, 0, stream>>>(cnt, excl, bsum);
    k_scan2  <<<1, 256, 0, stream>>>(bsum, boff);
    k_scan3  <<<256, 256, 0, stream>>>(excl, boff, rowptr, cursor);
    k_scatter<<<EE / 256, 256, 0, stream>>>(W_row, W_col, W_vals, cursor, ecol, evalv);

    // ---------------- encoder (f32)
    k_gemm<<<dim3(2, 512), 256, 0, stream>>>(features, enc_w1,             enc_b1,       Tenc, NN, 256, 128, 1);
    k_gemm<<<dim3(1, 512), 256, 0, stream>>>(Tenc,     enc_w2,             enc_b2,       rot0, NN, 128, 256, 0);
    k_gemm<<<dim3(2, 512), 256, 0, stream>>>(features, enc_w1 + 128 * 256, enc_b1 + 256, Tenc, NN, 256, 128, 1);
    k_gemm<<<dim3(1, 512), 256, 0, stream>>>(Tenc,     enc_w2 + 256 * 128, enc_b2 + 128, rot1, NN, 128, 256, 0);
    k_mean2<<<8192, 256, 0, stream>>>((const f4*)rot0, (const f4*)rot1, (f4*)h0);

    // ---------------- propagation loop (two SEQUENTIAL spmm dispatches; 3-buffer rotation)
    float* cur0 = rot0;
    float* cur1 = rot1;
    float* fre  = rot2;
    float* hbuf[4] = { h0, h1, h2, h3 };
    for (int p = 0; p < 3; ++p) {
        k_spmm<<<NN / 4, 256, 0, stream>>>(rowptr, ecol, evalv, cur0, fre);
        k_spmm<<<NN / 4, 256, 0, stream>>>(rowptr, ecol, evalv, cur1, cur0);
        k_bnstats2<<<dim3(512, 2), 128, 0, stream>>>(fre, cur0, psum, pssq);
        k_bnfin<<<1, 256, 0, stream>>>(psum, pssq, bn_gamma, bn_beta, d_a, d_c, 2, p);
        k_hidden<<<8192, 256, 0, stream>>>((const f4*)fre, (const f4*)cur0, d_a, d_c, (f4*)hbuf[1 + p]);
        float* t0 = fre; float* t1 = cur0; float* t2 = cur1;
        cur0 = t0; cur1 = t1; fre = t2;
    }

    // ---------------- concat MLP -> o_H, BN+relu in place
    k_concat<<<8192, 256, 0, stream>>>((const f4*)h0, (const f4*)h1, (const f4*)h2, (const f4*)h3,
                                       concat_w1, concat_b1, concat_w2, concat_b2, (f4*)o_H);
    k_bnstats2<<<dim3(512, 1), 128, 0, stream>>>(o_H, o_H, psum, pssq);
    k_bnfin<<<1, 256, 0, stream>>>(psum, pssq, bn_gamma, bn_beta, d_a, d_c, 1, 3);
    k_bnapply<<<8192, 256, 0, stream>>>((f4*)o_H, d_a, d_c);

    // ---------------- S_all
    k_gemm<<<dim3(1, 512), 256, 0, stream>>>(o_H, smlp_w1, smlp_b1, hid2, NN, 128, 128, 1);
    k_s<<<256, 256, 0, stream>>>(hid2, smlp_w2, smlp_b2, o_S);

    // ---------------- E_all, heads
    k_eall <<<512, 256, 0, stream>>>(o_S, o_H, d_off, o_E, E64);
    k_pred1<<<512, 64, 0, stream>>>(E64, final_w, final_b, d_gum, targets, d_corr,
                                    o_pred1, o_ind, d_cmask);
    k_q    <<<5120, 128, 0, stream>>>(o_E, proto_w1, proto_b1, proto_w2, proto_b2,
                                      d_cmask, o_Q, d_fm);
    k_pred2<<<512, 64, 0, stream>>>(E64, final_w, final_b, d_fm, o_pred2);

    (void)in_sizes; (void)n_in; (void)out_size; (void)ws_size;
}

// Round 10
// 1307.851 us; speedup vs baseline: 1.5693x; 1.0132x over previous
//
#include <hip/hip_runtime.h>
#include <math.h>

#define NN 65536
#define EE 1048576
#define GG 512
#define D  128

typedef float4 f4;

// ---------------------------------------------------------------- GEMM (fp32, 128x128 tile, 8x8 micro, split 4+4,
//   double-buffered LDS with a SINGLE barrier per K-step, optional fused mean epilogue)
// C[M,N] = act(A[M,K] @ B[K,N] + bias[N]); M%128==0, N%128==0, K%16==0
// if mix_dst: mix_dst = 0.5*(C_val + mix_src), same [M][N] shape (relu must be 0 for that use).
__global__ __launch_bounds__(256) void k_gemm(const float* __restrict__ A,
    const float* __restrict__ B, const float* __restrict__ bias,
    float* __restrict__ C, const float* __restrict__ mix_src, float* __restrict__ mix_dst,
    int M, int N, int K, int relu)
{
    __shared__ __align__(16) float As[2][16][132];
    __shared__ __align__(16) float Bs[2][16][132];
    int tid = threadIdx.x;
    int tx = tid & 15, ty = tid >> 4;
    int row0 = blockIdx.y * 128, col0 = blockIdx.x * 128;
    float acc[8][8];
#pragma unroll
    for (int i = 0; i < 8; ++i)
#pragma unroll
        for (int j = 0; j < 8; ++j) acc[i][j] = 0.f;
    int ar = tid >> 1, ac = (tid & 1) * 8;
    int br = tid >> 4, bc = (tid & 15) * 8;
    const float* aptr = A + (size_t)(row0 + ar) * K + ac;
    const float* bptr = B + (size_t)br * N + col0 + bc;

    // preload tile 0 and store to buffer 0
    f4 pa0 = *(const f4*)(aptr);
    f4 pa1 = *(const f4*)(aptr + 4);
    f4 pb0 = *(const f4*)(bptr);
    f4 pb1 = *(const f4*)(bptr + 4);
    As[0][ac + 0][ar] = pa0.x; As[0][ac + 1][ar] = pa0.y; As[0][ac + 2][ar] = pa0.z; As[0][ac + 3][ar] = pa0.w;
    As[0][ac + 4][ar] = pa1.x; As[0][ac + 5][ar] = pa1.y; As[0][ac + 6][ar] = pa1.z; As[0][ac + 7][ar] = pa1.w;
    *(f4*)&Bs[0][br][bc] = pb0; *(f4*)&Bs[0][br][bc + 4] = pb1;
    __syncthreads();

    int cur = 0;
    for (int k0 = 0; k0 < K; k0 += 16) {
        int last = (k0 + 16 >= K);
        if (!last) {  // issue next tile's global loads; they complete during compute
            pa0 = *(const f4*)(aptr + k0 + 16);
            pa1 = *(const f4*)(aptr + k0 + 16 + 4);
            pb0 = *(const f4*)(bptr + (size_t)(k0 + 16) * N);
            pb1 = *(const f4*)(bptr + (size_t)(k0 + 16) * N + 4);
        }
        const float (*Ac)[132] = As[cur];
        const float (*Bc)[132] = Bs[cur];
#pragma unroll
        for (int kk = 0; kk < 16; ++kk) {
            float a[8], b[8];
            *(f4*)&a[0] = *(const f4*)&Ac[kk][ty * 4];
            *(f4*)&a[4] = *(const f4*)&Ac[kk][64 + ty * 4];
            *(f4*)&b[0] = *(const f4*)&Bc[kk][tx * 4];
            *(f4*)&b[4] = *(const f4*)&Bc[kk][64 + tx * 4];
#pragma unroll
            for (int i = 0; i < 8; ++i)
#pragma unroll
                for (int j = 0; j < 8; ++j) acc[i][j] = fmaf(a[i], b[j], acc[i][j]);
        }
        if (!last) {
            int nxt = cur ^ 1;
            As[nxt][ac + 0][ar] = pa0.x; As[nxt][ac + 1][ar] = pa0.y; As[nxt][ac + 2][ar] = pa0.z; As[nxt][ac + 3][ar] = pa0.w;
            As[nxt][ac + 4][ar] = pa1.x; As[nxt][ac + 5][ar] = pa1.y; As[nxt][ac + 6][ar] = pa1.z; As[nxt][ac + 7][ar] = pa1.w;
            *(f4*)&Bs[nxt][br][bc] = pb0; *(f4*)&Bs[nxt][br][bc + 4] = pb1;
            __syncthreads();   // single barrier per K-step
            cur = nxt;
        }
    }

    f4 bia0 = *(const f4*)(bias + col0 + tx * 4);
    f4 bia1 = *(const f4*)(bias + col0 + 64 + tx * 4);
#pragma unroll
    for (int i = 0; i < 8; ++i) {
        int r = row0 + ((i < 4) ? (ty * 4 + i) : (64 + ty * 4 + i - 4));
        f4 v0, v1;
#pragma unroll
        for (int j = 0; j < 4; ++j) {
            float u0 = acc[i][j] + (&bia0.x)[j];
            float u1 = acc[i][j + 4] + (&bia1.x)[j];
            if (relu) { u0 = fmaxf(u0, 0.f); u1 = fmaxf(u1, 0.f); }
            (&v0.x)[j] = u0; (&v1.x)[j] = u1;
        }
        *(f4*)(C + (size_t)r * N + col0 + tx * 4) = v0;
        *(f4*)(C + (size_t)r * N + col0 + 64 + tx * 4) = v1;
        if (mix_dst) {  // fused hidden_rep[0] mean (bit-identical to k_mean2)
            f4 m0 = *(const f4*)(mix_src + (size_t)r * N + col0 + tx * 4);
            f4 m1 = *(const f4*)(mix_src + (size_t)r * N + col0 + 64 + tx * 4);
            f4 w0, w1;
#pragma unroll
            for (int j = 0; j < 4; ++j) {
                (&w0.x)[j] = 0.5f * ((&v0.x)[j] + (&m0.x)[j]);
                (&w1.x)[j] = 0.5f * ((&v1.x)[j] + (&m1.x)[j]);
            }
            *(f4*)(mix_dst + (size_t)r * N + col0 + tx * 4) = w0;
            *(f4*)(mix_dst + (size_t)r * N + col0 + 64 + tx * 4) = w1;
        }
    }
}

// ---------------------------------------------------------------- CSR build
__global__ __launch_bounds__(256) void k_hist(const int* __restrict__ Wr, int* __restrict__ cnt)
{
    int e = blockIdx.x * 256 + threadIdx.x;
    if (e < EE) atomicAdd(&cnt[Wr[e]], 1);
}

__global__ __launch_bounds__(256) void k_scan1(const int* __restrict__ cnt,
    int* __restrict__ excl, int* __restrict__ bsum)
{
    __shared__ int s[256];
    int b = blockIdx.x, t = threadIdx.x;
    int v = cnt[b * 256 + t];
    s[t] = v; __syncthreads();
    for (int o = 1; o < 256; o <<= 1) {
        int x = (t >= o) ? s[t - o] : 0;
        __syncthreads();
        s[t] += x;
        __syncthreads();
    }
    excl[b * 256 + t] = s[t] - v;
    if (t == 255) bsum[b] = s[255];
}

__global__ void k_scan2(const int* __restrict__ bsum, int* __restrict__ boff)
{
    __shared__ int s[256];
    int t = threadIdx.x;
    int v = bsum[t]; s[t] = v; __syncthreads();
    for (int o = 1; o < 256; o <<= 1) {
        int x = (t >= o) ? s[t - o] : 0;
        __syncthreads();
        s[t] += x;
        __syncthreads();
    }
    boff[t] = s[t] - v;
}

__global__ __launch_bounds__(256) void k_scan3(const int* __restrict__ excl, const int* __restrict__ boff,
    int* __restrict__ rowptr, int* __restrict__ cursor)
{
    int i = blockIdx.x * 256 + threadIdx.x;
    int v = excl[i] + boff[i >> 8];
    rowptr[i] = v; cursor[i] = v;
    if (i == 0) rowptr[NN] = EE;
}

__global__ __launch_bounds__(256) void k_scatter(const int* __restrict__ Wr, const int* __restrict__ Wc,
    const float* __restrict__ Wv, int* __restrict__ cursor, int* __restrict__ ecol, float* __restrict__ ev)
{
    int e = blockIdx.x * 256 + threadIdx.x;
    if (e >= EE) return;
    int r = Wr[e];
    int p = atomicAdd(&cursor[r], 1);
    ecol[p] = Wc[e]; ev[p] = Wv[e];
}

// ---------------------------------------------------------------- SpMM (CSR, wave/row, 4-edge chunks, dual matrix)
// SAFETY (G16, round-6 lesson): Y0,Y1 must be disjoint from BOTH X0,X1.
__global__ __launch_bounds__(256) void k_spmm2(const int* __restrict__ rowptr,
    const int* __restrict__ ecol, const float* __restrict__ eval,
    const float* __restrict__ X0, float* __restrict__ Y0,
    const float* __restrict__ X1, float* __restrict__ Y1)
{
    int row = blockIdx.x * 4 + (threadIdx.x >> 6);
    int lane = threadIdx.x & 63;
    const float* __restrict__ X = blockIdx.y ? X1 : X0;
    float* __restrict__ Y = blockIdx.y ? Y1 : Y0;
    int s = rowptr[row], e = rowptr[row + 1];
    float a0 = 0.f, a1 = 0.f;
    int i = s;
    for (; i + 4 <= e; i += 4) {
        int   c0 = ecol[i], c1 = ecol[i + 1], c2 = ecol[i + 2], c3 = ecol[i + 3];
        float w0 = eval[i], w1 = eval[i + 1], w2 = eval[i + 2], w3 = eval[i + 3];
        float2 x0 = *(const float2*)(X + (size_t)c0 * D + lane * 2);
        float2 x1 = *(const float2*)(X + (size_t)c1 * D + lane * 2);
        float2 x2 = *(const float2*)(X + (size_t)c2 * D + lane * 2);
        float2 x3 = *(const float2*)(X + (size_t)c3 * D + lane * 2);
        a0 = fmaf(w0, x0.x, a0); a1 = fmaf(w0, x0.y, a1);
        a0 = fmaf(w1, x1.x, a0); a1 = fmaf(w1, x1.y, a1);
        a0 = fmaf(w2, x2.x, a0); a1 = fmaf(w2, x2.y, a1);
        a0 = fmaf(w3, x3.x, a0); a1 = fmaf(w3, x3.y, a1);
    }
    for (; i < e; ++i) {
        int cc = ecol[i];
        float w = eval[i];
        float2 x = *(const float2*)(X + (size_t)cc * D + lane * 2);
        a0 = fmaf(w, x.x, a0);
        a1 = fmaf(w, x.y, a1);
    }
    *(float2*)(Y + (size_t)row * D + lane * 2) = make_float2(a0, a1);
}

// ---------------------------------------------------------------- BN stats (dual matrix read-only fuse, f64 partials)
__global__ __launch_bounds__(128) void k_bnstats2(const float* __restrict__ X0, const float* __restrict__ X1,
    double* __restrict__ psum, double* __restrict__ pssq)
{
    const float* __restrict__ X = blockIdx.y ? X1 : X0;
    int d = threadIdx.x;
    int r0 = blockIdx.x * 128;
    double s = 0.0, q = 0.0;
#pragma unroll 4
    for (int r = r0; r < r0 + 128; ++r) {
        double v = (double)X[(size_t)r * D + d];
        s += v; q = fma(v, v, q);
    }
    psum[blockIdx.y * 65536 + blockIdx.x * 128 + d] = s;
    pssq[blockIdx.y * 65536 + blockIdx.x * 128 + d] = q;
}

__global__ void k_bnfin(const double* __restrict__ psum, const double* __restrict__ pssq,
    const float* __restrict__ gamma, const float* __restrict__ beta,
    double* __restrict__ a, double* __restrict__ c, int nb, int layer)
{
    int t = threadIdx.x;
    if (t >= nb * 128) return;
    int blk = t >> 7, d = t & 127;
    const double* ps = psum + blk * 65536;
    const double* pq = pssq + blk * 65536;
    double s = 0.0, q = 0.0;
    for (int j = 0; j < 512; ++j) { s += ps[j * 128 + d]; q += pq[j * 128 + d]; }
    double m = s * (1.0 / 65536.0);
    double v = q * (1.0 / 65536.0) - m * m;
    double aa = (double)gamma[layer * 128 + d] / sqrt(v + 1e-5);
    a[t] = aa;
    c[t] = (double)beta[layer * 128 + d] - m * aa;
}

// ---------------------------------------------------------------- elementwise (f32, f4)
// NOTE: o may alias p1 (same-index elementwise RMW is safe) -> no __restrict__ on p1/o.
__global__ __launch_bounds__(256) void k_hidden(const f4* __restrict__ p0, const f4* p1,
    const double* __restrict__ a, const double* __restrict__ c, f4* o)
{
    int i = blockIdx.x * 256 + threadIdx.x;
    int d4 = (i & 31) * 4;
    f4 x = p0[i], y = p1[i];
    f4 r;
#pragma unroll
    for (int j = 0; j < 4; ++j) {
        float a0 = (float)a[d4 + j], c0 = (float)c[d4 + j];
        float a1 = (float)a[128 + d4 + j], c1 = (float)c[128 + d4 + j];
        float xv = (&x.x)[j], yv = (&y.x)[j];
        (&r.x)[j] = 0.5f * (fmaxf(fmaf(xv, a0, c0), 0.f) + fmaxf(fmaf(yv, a1, c1), 0.f));
    }
    o[i] = r;
}

__global__ __launch_bounds__(256) void k_bnapply(f4* __restrict__ H,
    const double* __restrict__ a, const double* __restrict__ c)
{
    int i = blockIdx.x * 256 + threadIdx.x;
    int d4 = (i & 31) * 4;
    f4 x = H[i];
#pragma unroll
    for (int j = 0; j < 4; ++j) {
        float a0 = (float)a[d4 + j], c0 = (float)c[d4 + j];
        (&x.x)[j] = fmaxf(fmaf((&x.x)[j], a0, c0), 0.f);
    }
    H[i] = x;
}

// ---------------------------------------------------------------- concat MLP (f32, 4 elems/thread, f4 weight reads)
__global__ __launch_bounds__(256) void k_concat(const f4* __restrict__ h0, const f4* __restrict__ h1,
    const f4* __restrict__ h2, const f4* __restrict__ h3,
    const float* __restrict__ w1, const float* __restrict__ b1,
    const float* __restrict__ w2, const float* __restrict__ b2,
    f4* __restrict__ Hpre)
{
    __shared__ __align__(16) float sw0[128], sw1_[128], sw2_[128], sw3[128], sv[128], sb[128];
    int t = threadIdx.x;
    if (t < 128) {
        sw0[t] = w1[t];        sw1_[t] = w1[128 + t];
        sw2_[t] = w1[256 + t]; sw3[t]  = w1[384 + t];
        sv[t]  = w2[t];        sb[t]   = b1[t];
    }
    __syncthreads();
    int i = blockIdx.x * 256 + t;  // f4 units, < N*D/4
    f4 x0 = h0[i], x1 = h1[i], x2 = h2[i], x3 = h3[i];
    float bb2 = b2[0];
    float acc0 = bb2, acc1 = bb2, acc2 = bb2, acc3 = bb2;
    for (int h4 = 0; h4 < D; h4 += 4) {
        f4 cw0 = *(const f4*)&sw0[h4];
        f4 cw1 = *(const f4*)&sw1_[h4];
        f4 cw2 = *(const f4*)&sw2_[h4];
        f4 cw3 = *(const f4*)&sw3[h4];
        f4 cbb = *(const f4*)&sb[h4];
        f4 cvv = *(const f4*)&sv[h4];
#pragma unroll
        for (int j = 0; j < 4; ++j) {
            float w0 = (&cw0.x)[j], ww1 = (&cw1.x)[j], ww2 = (&cw2.x)[j], w3 = (&cw3.x)[j];
            float bb = (&cbb.x)[j], vv = (&cvv.x)[j];
            float t0 = fmaf(x3.x, w3, fmaf(x2.x, ww2, fmaf(x1.x, ww1, fmaf(x0.x, w0, bb))));
            float t1 = fmaf(x3.y, w3, fmaf(x2.y, ww2, fmaf(x1.y, ww1, fmaf(x0.y, w0, bb))));
            float t2 = fmaf(x3.z, w3, fmaf(x2.z, ww2, fmaf(x1.z, ww1, fmaf(x0.z, w0, bb))));
            float t3 = fmaf(x3.w, w3, fmaf(x2.w, ww2, fmaf(x1.w, ww1, fmaf(x0.w, w0, bb))));
            acc0 = fmaf(fmaxf(t0, 0.f), vv, acc0);
            acc1 = fmaf(fmaxf(t1, 0.f), vv, acc1);
            acc2 = fmaf(fmaxf(t2, 0.f), vv, acc2);
            acc3 = fmaf(fmaxf(t3, 0.f), vv, acc3);
        }
    }
    f4 r; r.x = acc0; r.y = acc1; r.z = acc2; r.w = acc3;
    Hpre[i] = r;
}

// ---------------------------------------------------------------- S = softmax(hid @ w2 + b2) (f32)
__global__ __launch_bounds__(256) void k_s(const float* __restrict__ hid,
    const float* __restrict__ w2, const float* __restrict__ b2, float* __restrict__ S)
{
    int n = blockIdx.x * 256 + threadIdx.x;
    if (n >= NN) return;
    const float* hr = hid + (size_t)n * D;
    float s[10];
#pragma unroll
    for (int k = 0; k < 10; ++k) s[k] = b2[k];
    for (int h = 0; h < D; h += 4) {
        f4 hv = *(const f4*)(hr + h);
#pragma unroll
        for (int k = 0; k < 10; ++k) {
            s[k] = fmaf(hv.x, w2[(h + 0) * 10 + k], s[k]);
            s[k] = fmaf(hv.y, w2[(h + 1) * 10 + k], s[k]);
            s[k] = fmaf(hv.z, w2[(h + 2) * 10 + k], s[k]);
            s[k] = fmaf(hv.w, w2[(h + 3) * 10 + k], s[k]);
        }
    }
    float m = s[0];
#pragma unroll
    for (int k = 1; k < 10; ++k) m = fmaxf(m, s[k]);
    float e[10], sum = 0.f;
#pragma unroll
    for (int k = 0; k < 10; ++k) { e[k] = expf(s[k] - m); sum += e[k]; }
    float inv = 1.f / sum;
#pragma unroll
    for (int k = 0; k < 10; ++k) S[(size_t)n * 10 + k] = e[k] * inv;
}

// ---------------------------------------------------------------- E_all (f32 in, f64 accum, dual store)
__global__ __launch_bounds__(256) void k_eall(const float* __restrict__ S, const float* __restrict__ H,
    const int* __restrict__ off, float* __restrict__ Eo, double* __restrict__ E64)
{
    int g = blockIdx.x;
    int d = threadIdx.x & 127;
    int half = threadIdx.x >> 7;
    double acc[5] = {0.0, 0.0, 0.0, 0.0, 0.0};
    int s0 = off[g], s1 = off[g + 1];
    for (int n = s0; n < s1; ++n) {
        double hv = (double)H[(size_t)n * D + d];
#pragma unroll
        for (int j = 0; j < 5; ++j) acc[j] = fma((double)S[(size_t)n * 10 + half * 5 + j], hv, acc[j]);
    }
#pragma unroll
    for (int j = 0; j < 5; ++j) {
        size_t o = (size_t)g * 1280 + (half * 5 + j) * D + d;
        Eo[o] = (float)acc[j];
        E64[o] = acc[j];
    }
}

// ---------------------------------------------------------------- graph offsets
__global__ void k_off(const int* __restrict__ gi, int* __restrict__ off)
{
    int g = blockIdx.x * 256 + threadIdx.x;
    if (g > GG) return;
    int lo = 0, hi = NN;
    while (lo < hi) { int mid = (lo + hi) >> 1; if (gi[mid] < g) lo = mid + 1; else hi = mid; }
    off[g] = lo;
}

// ---------------------------------------------------------------- corr
__global__ void k_corr(const float* __restrict__ ci, const float* __restrict__ ca, float* __restrict__ corr)
{
    int t = threadIdx.x;
    if (t >= 160) return;
    int r = t / 16, c = t % 16;
    double m = -1e300;
    for (int i = 0; i < 10; ++i) m = fmax(m, (double)ci[i * 16 + c]);
    double s = 0.0;
    for (int i = 0; i < 10; ++i) s += exp((double)ci[i * 16 + c] - m);
    double vi = exp((double)ci[r * 16 + c] - m) / s;
    double m2 = -1e300;
    for (int j = 0; j < 16; ++j) m2 = fmax(m2, (double)ca[r * 16 + j]);
    double s2 = 0.0;
    for (int j = 0; j < 16; ++j) s2 += exp((double)ca[r * 16 + j] - m2);
    double va = exp((double)ca[r * 16 + c] - m2) / s2;
    corr[t] = (float)(vi * va);
}

// ---------------------------------------------------------------- JAX threefry gumbel — PARTITIONABLE (verified)
__device__ __forceinline__ unsigned tf_rotl(unsigned x, unsigned n) { return (x << n) | (x >> (32u - n)); }

__global__ void k_gumbel(double* __restrict__ out)
{
    int i = blockIdx.x * 256 + threadIdx.x;
    if (i >= 5120) return;
    unsigned x0 = 0u;              // hi32 of 64-bit counter
    unsigned x1 = (unsigned)i;     // lo32
    const unsigned ks0 = 0u, ks1 = 42u;
    const unsigned ks2 = 0x1BD11BDAu ^ ks0 ^ ks1;
    x0 += ks0; x1 += ks1;
#define TF_ROUND(rr) { x0 += x1; x1 = tf_rotl(x1, rr); x1 ^= x0; }
    TF_ROUND(13) TF_ROUND(15) TF_ROUND(26) TF_ROUND(6)
    x0 += ks1; x1 += ks2 + 1u;
    TF_ROUND(17) TF_ROUND(29) TF_ROUND(16) TF_ROUND(24)
    x0 += ks2; x1 += ks0 + 2u;
    TF_ROUND(13) TF_ROUND(15) TF_ROUND(26) TF_ROUND(6)
    x0 += ks0; x1 += ks1 + 3u;
    TF_ROUND(17) TF_ROUND(29) TF_ROUND(16) TF_ROUND(24)
    x0 += ks1; x1 += ks2 + 4u;
    TF_ROUND(13) TF_ROUND(15) TF_ROUND(26) TF_ROUND(6)
    x0 += ks2; x1 += ks0 + 5u;
#undef TF_ROUND
    unsigned bits = x0 ^ x1;       // partitionable 32-bit combine
    unsigned fb = (bits >> 9) | 0x3f800000u;
    float f = __uint_as_float(fb) - 1.0f;
    const float tinyf = 1.1754943508222875e-38f;
    float u32v = fmaxf(tinyf, f * (1.0f - tinyf) + tinyf);
    out[i] = -log(-log((double)u32v));
}

// ---------------------------------------------------------------- pred1 + sampling (f64)
__global__ __launch_bounds__(64) void k_pred1(const double* __restrict__ E64, const float* __restrict__ fw,
    const float* __restrict__ fb, const double* __restrict__ gum, const int* __restrict__ tgt,
    const float* __restrict__ corr, float* __restrict__ pred1, float* __restrict__ ind,
    float* __restrict__ cmask)
{
    int g = blockIdx.x;
    int l = threadIdx.x;
    double acc[10];
#pragma unroll
    for (int c = 0; c < 10; ++c) acc[c] = 0.0;
    for (int i = l; i < 1280; i += 64) {
        double e = E64[(size_t)g * 1280 + i];
#pragma unroll
        for (int c = 0; c < 10; ++c) acc[c] = fma(e, (double)fw[i * 10 + c], acc[c]);
    }
#pragma unroll
    for (int c = 0; c < 10; ++c) {
        double v = acc[c];
        for (int o = 32; o > 0; o >>= 1) v += __shfl_down(v, o, 64);
        acc[c] = v;
    }
    if (l == 0) {
        double best = -1e300; int bi = 0;
        for (int c = 0; c < 10; ++c) {
            double p = acc[c] + (double)fb[c];
            pred1[g * 10 + c] = (float)p;
            double y = p + gum[g * 10 + c];
            if (y > best) { best = y; bi = c; }
        }
        ind[g] = (bi == tgt[g]) ? 1.f : 0.f;
        for (int f = 0; f < 16; ++f) cmask[g * 16 + f] = corr[bi * 16 + f];
    }
}

// ---------------------------------------------------------------- Q + feature_mask (f32)
__global__ __launch_bounds__(128) void k_q(const float* __restrict__ Eo, const float* __restrict__ w1,
    const float* __restrict__ b1, const float* __restrict__ w2, const float* __restrict__ b2,
    const float* __restrict__ cmask, float* __restrict__ Q, float* __restrict__ fm)
{
    int gk = blockIdx.x;
    int g = gk / 10;
    int h = threadIdx.x;
    __shared__ float e[128];
    __shared__ float hh[128];
    __shared__ float qv[16];
    __shared__ float pr[16];
    e[h] = Eo[(size_t)gk * D + h];
    __syncthreads();
    float acc = b1[h];
#pragma unroll 8
    for (int d = 0; d < D; ++d) acc = fmaf(e[d], w1[d * D + h], acc);
    hh[h] = fmaxf(acc, 0.f);
    __syncthreads();
    if (h < 16) {
        float s = b2[h];
        for (int d = 0; d < D; ++d) s = fmaf(hh[d], w2[d * 16 + h], s);
        qv[h] = s;
    }
    __syncthreads();
    if (h < 16) {
        float m = qv[0];
        for (int f = 1; f < 16; ++f) m = fmaxf(m, qv[f]);
        pr[h] = expf(qv[h] - m);
    }
    __syncthreads();
    if (h < 16) {
        float s = 0.f;
        for (int f = 0; f < 16; ++f) s += pr[f];
        float q = pr[h] / s;
        Q[(size_t)gk * 16 + h] = q;
        qv[h] = q * cmask[g * 16 + h];
    }
    __syncthreads();
    if (h == 0) {
        float s = 0.f;
        for (int f = 0; f < 16; ++f) s += qv[f];
        fm[gk] = s;
    }
}

// ---------------------------------------------------------------- pred2 (f64 accum from E64)
__global__ __launch_bounds__(64) void k_pred2(const double* __restrict__ E64, const float* __restrict__ fw,
    const float* __restrict__ fb, const float* __restrict__ fm, float* __restrict__ pred2)
{
    int g = blockIdx.x;
    int l = threadIdx.x;
    double acc[10];
#pragma unroll
    for (int c = 0; c < 10; ++c) acc[c] = 0.0;
    for (int i = l; i < 1280; i += 64) {
        int k = i >> 7;
        double e = E64[(size_t)g * 1280 + i] * (double)fm[g * 10 + k];
#pragma unroll
        for (int c = 0; c < 10; ++c) acc[c] = fma(e, (double)fw[i * 10 + c], acc[c]);
    }
#pragma unroll
    for (int c = 0; c < 10; ++c) {
        double v = acc[c];
        for (int o = 32; o > 0; o >>= 1) v += __shfl_down(v, o, 64);
        acc[c] = v;
    }
    if (l == 0)
        for (int c = 0; c < 10; ++c) pred2[g * 10 + c] = (float)(acc[c] + (double)fb[c]);
}

// ================================================================ host
extern "C" void kernel_launch(void* const* d_in, const int* in_sizes, int n_in,
                              void* d_out, int out_size, void* d_ws, size_t ws_size,
                              hipStream_t stream)
{
    const float* features = (const float*)d_in[0];
    const int*   W_row    = (const int*)d_in[1];
    const int*   W_col    = (const int*)d_in[2];
    const float* W_vals   = (const float*)d_in[3];
    const int*   gi       = (const int*)d_in[4];
    const int*   targets  = (const int*)d_in[5];
    const float* enc_w1   = (const float*)d_in[6];
    const float* enc_b1   = (const float*)d_in[7];
    const float* enc_w2   = (const float*)d_in[8];
    const float* enc_b2   = (const float*)d_in[9];
    const float* bn_gamma = (const float*)d_in[10];
    const float* bn_beta  = (const float*)d_in[11];
    const float* concat_w1= (const float*)d_in[12];
    const float* concat_b1= (const float*)d_in[13];
    const float* concat_w2= (const float*)d_in[14];
    const float* concat_b2= (const float*)d_in[15];
    const float* smlp_w1  = (const float*)d_in[16];
    const float* smlp_b1  = (const float*)d_in[17];
    const float* smlp_w2  = (const float*)d_in[18];
    const float* smlp_b2  = (const float*)d_in[19];
    const float* proto_w1 = (const float*)d_in[20];
    const float* proto_b1 = (const float*)d_in[21];
    const float* proto_w2 = (const float*)d_in[22];
    const float* proto_b2 = (const float*)d_in[23];
    const float* final_w  = (const float*)d_in[24];
    const float* final_b  = (const float*)d_in[25];
    const float* corr_i   = (const float*)d_in[26];
    const float* corr_a   = (const float*)d_in[27];

    float* out = (float*)d_out;
    float* o_pred1 = out + 0;
    float* o_pred2 = out + 5120;
    float* o_S     = out + 10240;
    float* o_H     = out + 665600;
    float* o_ind   = out + 9054208;
    float* o_E     = out + 9054720;
    float* o_Q     = out + 9710080;

    // ---------------- workspace arena (total ~240 MiB — proven fit; do NOT grow: round-8 crash)
    char* base = (char*)d_ws;
    size_t off = 0;
    auto alloc = [&](size_t n) -> char* {
        char* r = base + off;
        off = (off + n + 255) & ~(size_t)255;
        return r;
    };
    int*    d_off   = (int*)alloc(513 * 4);
    double* d_a     = (double*)alloc(256 * 8);
    double* d_c     = (double*)alloc(256 * 8);
    double* d_gum   = (double*)alloc(5120 * 8);
    float*  d_corr  = (float*)alloc(160 * 4);
    float*  d_cmask = (float*)alloc(512 * 16 * 4);
    float*  d_fm    = (float*)alloc(5120 * 4);
    double* psum    = (double*)alloc(2 * 512 * 128 * 8);
    double* pssq    = (double*)alloc(2 * 512 * 128 * 8);
    int*    cnt     = (int*)alloc((size_t)NN * 4);
    int*    excl    = (int*)alloc((size_t)NN * 4);
    int*    bsum    = (int*)alloc(256 * 4);
    int*    boff    = (int*)alloc(256 * 4);
    int*    rowptr  = (int*)alloc((size_t)(NN + 1) * 4);
    int*    cursor  = (int*)alloc((size_t)NN * 4);
    int*    ecol    = (int*)alloc((size_t)EE * 4);
    float*  evalv   = (float*)alloc((size_t)EE * 4);
    double* E64     = (double*)alloc((size_t)GG * 1280 * 8);   // 5.24 MB

    const size_t SZ = (size_t)NN * D * 4;   // 32 MiB per f32 tensor
    float* rot0 = (float*)alloc(SZ);
    float* rot1 = (float*)alloc(SZ);
    float* rot2 = (float*)alloc(SZ);
    float* h0   = (float*)alloc(SZ);
    float* h1   = (float*)alloc(SZ);
    float* h2   = (float*)alloc(SZ);
    float* h3   = (float*)alloc(SZ);
    float* Tenc = h2;        // N x 256 f32 spans h2+h3 (dead after encoder; NOT h0 — mean fuses into h0)
    float* hid2 = rot0;      // smlp hidden reuses rot region after prop loop

    // ---------------- small precomputations
    k_off   <<<3, 256, 0, stream>>>(gi, d_off);
    k_corr  <<<1, 256, 0, stream>>>(corr_i, corr_a, d_corr);
    k_gumbel<<<20, 256, 0, stream>>>(d_gum);

    // ---------------- CSR build
    hipMemsetAsync(cnt, 0, (size_t)NN * 4, stream);
    k_hist   <<<EE / 256, 256, 0, stream>>>(W_row, cnt);
    k_scan1  <<<256, 256, 0, stream>>>(cnt, excl, bsum);
    k_scan2  <<<1, 256, 0, stream>>>(bsum, boff);
    k_scan3  <<<256, 256, 0, stream>>>(excl, boff, rowptr, cursor);
    k_scatter<<<EE / 256, 256, 0, stream>>>(W_row, W_col, W_vals, cursor, ecol, evalv);

    // ---------------- encoder (f32); 4th GEMM fuses hidden_rep[0] = 0.5*(rot0+rot1) -> h0
    k_gemm<<<dim3(2, 512), 256, 0, stream>>>(features, enc_w1,             enc_b1,       Tenc, nullptr, nullptr, NN, 256, 128, 1);
    k_gemm<<<dim3(1, 512), 256, 0, stream>>>(Tenc,     enc_w2,             enc_b2,       rot0, nullptr, nullptr, NN, 128, 256, 0);
    k_gemm<<<dim3(2, 512), 256, 0, stream>>>(features, enc_w1 + 128 * 256, enc_b1 + 256, Tenc, nullptr, nullptr, NN, 256, 128, 1);
    k_gemm<<<dim3(1, 512), 256, 0, stream>>>(Tenc,     enc_w2 + 256 * 128, enc_b2 + 128, rot1, rot0, h0,         NN, 128, 256, 0);

    // ---------------- propagation loop: fused dual-SpMM, zero extra memory.
    // p=0: (rot0,rot1)->(rot2,h2), hidden->h1
    // p=1: (rot2,h2)->(rot0,rot1), hidden->h2   (h2 read by spmm BEFORE hidden overwrites it)
    // p=2: (rot0,rot1)->(rot2,h3), hidden(rot2,h3)->h3 (in-place elementwise, same-index, safe)
    {
        float* hbuf[4] = { h0, h1, h2, h3 };
        float* curA = rot0; float* curB = rot1;
        float* nxtA[3] = { rot2, rot0, rot2 };
        float* nxtB[3] = { h2,   rot1, h3   };
        for (int p = 0; p < 3; ++p) {
            float* nA = nxtA[p];
            float* nB = nxtB[p];
            k_spmm2<<<dim3(NN / 4, 2), 256, 0, stream>>>(rowptr, ecol, evalv, curA, nA, curB, nB);
            k_bnstats2<<<dim3(512, 2), 128, 0, stream>>>(nA, nB, psum, pssq);
            k_bnfin<<<1, 256, 0, stream>>>(psum, pssq, bn_gamma, bn_beta, d_a, d_c, 2, p);
            k_hidden<<<8192, 256, 0, stream>>>((const f4*)nA, (const f4*)nB, d_a, d_c, (f4*)hbuf[1 + p]);
            curA = nA; curB = nB;
        }
    }

    // ---------------- concat MLP -> o_H, BN+relu in place
    k_concat<<<8192, 256, 0, stream>>>((const f4*)h0, (const f4*)h1, (const f4*)h2, (const f4*)h3,
                                       concat_w1, concat_b1, concat_w2, concat_b2, (f4*)o_H);
    k_bnstats2<<<dim3(512, 1), 128, 0, stream>>>(o_H, o_H, psum, pssq);
    k_bnfin<<<1, 256, 0, stream>>>(psum, pssq, bn_gamma, bn_beta, d_a, d_c, 1, 3);
    k_bnapply<<<8192, 256, 0, stream>>>((f4*)o_H, d_a, d_c);

    // ---------------- S_all
    k_gemm<<<dim3(1, 512), 256, 0, stream>>>(o_H, smlp_w1, smlp_b1, hid2, nullptr, nullptr, NN, 128, 128, 1);
    k_s<<<256, 256, 0, stream>>>(hid2, smlp_w2, smlp_b2, o_S);

    // ---------------- E_all, heads
    k_eall <<<512, 256, 0, stream>>>(o_S, o_H, d_off, o_E, E64);
    k_pred1<<<512, 64, 0, stream>>>(E64, final_w, final_b, d_gum, targets, d_corr,
                                    o_pred1, o_ind, d_cmask);
    k_q    <<<5120, 128, 0, stream>>>(o_E, proto_w1, proto_b1, proto_w2, proto_b2,
                                      d_cmask, o_Q, d_fm);
    k_pred2<<<512, 64, 0, stream>>>(E64, final_w, final_b, d_fm, o_pred2);

    (void)in_sizes; (void)n_in; (void)out_size; (void)ws_size;
}